// Round 5
// baseline (768.261 us; speedup 1.0000x reference)
//
#include <hip/hip_runtime.h>
#include <hip/hip_bf16.h>
#include <math.h>

#define NN 50000
#define EE 800000
#define DD 128
#define HH 8
#define DKK 16

typedef __attribute__((ext_vector_type(8))) short short8;
typedef __attribute__((ext_vector_type(4))) float f32x4;
typedef __attribute__((ext_vector_type(4))) unsigned short ushort4v;
typedef __attribute__((ext_vector_type(8))) unsigned short ushort8v;

static __device__ __forceinline__ unsigned short f2bf(float x) {
  __hip_bfloat16 h = __float2bfloat16(x);   // RNE
  return *reinterpret_cast<unsigned short*>(&h);
}
static __device__ __forceinline__ float bf2f(unsigned short u) {
  return __uint_as_float(((unsigned int)u) << 16);
}

// ---------------------------------------------------------------------------
// Bucket-by-dst prep: histogram -> exclusive scan -> permutation fill.
// ---------------------------------------------------------------------------
__global__ __launch_bounds__(256) void hist_kernel(const int* __restrict__ dst,
                                                   int* __restrict__ cnt) {
  int i = blockIdx.x * 256 + threadIdx.x;
  if (i < EE) atomicAdd(&cnt[dst[i]], 1);
}

__global__ __launch_bounds__(1024) void scan_kernel(const int* __restrict__ cnt,
                                                    int* __restrict__ rowptr) {
  __shared__ int part[1024];
  const int tid = threadIdx.x;
  const int per = (NN + 1023) / 1024;       // 49
  const int base = tid * per;
  int s = 0;
  for (int j = 0; j < per; ++j) {
    int idx = base + j;
    if (idx < NN) s += cnt[idx];
  }
  part[tid] = s;
  __syncthreads();
  for (int off = 1; off < 1024; off <<= 1) {  // Hillis-Steele inclusive scan
    int v = (tid >= off) ? part[tid - off] : 0;
    __syncthreads();
    part[tid] += v;
    __syncthreads();
  }
  int run = (tid == 0) ? 0 : part[tid - 1];   // exclusive prefix
  for (int j = 0; j < per; ++j) {
    int idx = base + j;
    if (idx < NN) { rowptr[idx] = run; run += cnt[idx]; }
  }
  if (tid == 1023) rowptr[NN] = part[1023];   // == EE
}

__global__ __launch_bounds__(256) void fill_kernel(const int* __restrict__ dst,
                                                   const int* __restrict__ rowptr,
                                                   int* __restrict__ cur,
                                                   int* __restrict__ perm) {
  int i = blockIdx.x * 256 + threadIdx.x;
  if (i < EE) {
    int d = dst[i];
    int slot = atomicAdd(&cur[d], 1);
    perm[rowptr[d] + slot] = i;
  }
}

// ---------------------------------------------------------------------------
// Prep: WT[j][c] = bf16(W[c][j]) for Wq, Wk, Wv (each 32KB bf16, L2-resident)
// ---------------------------------------------------------------------------
__global__ void prep_w_kernel(const float* __restrict__ Wq,
                              const float* __restrict__ Wk,
                              const float* __restrict__ Wv,
                              unsigned short* __restrict__ WqT,
                              unsigned short* __restrict__ WkT,
                              unsigned short* __restrict__ WvT) {
  int c = blockIdx.x & 127;
  int m = blockIdx.x >> 7;
  int j = threadIdx.x;
  const float* W = (m == 0) ? Wq : (m == 1) ? Wk : Wv;
  unsigned short* o = (m == 0) ? WqT : (m == 1) ? WkT : WvT;
  o[j * DD + c] = f2bf(W[c * DD + j]);
}

// ---------------------------------------------------------------------------
// Kernel 1: node projections via MFMA.  Qh = bf16(q @ Wq), Vh = bf16(v @ Wv).
// ---------------------------------------------------------------------------
__global__ __launch_bounds__(512) void node_proj_kernel(
    const float* __restrict__ q, const float* __restrict__ v,
    const unsigned short* __restrict__ WqT, const unsigned short* __restrict__ WvT,
    unsigned short* __restrict__ Qh, unsigned short* __restrict__ Vh)
{
  __shared__ __align__(16) unsigned short xl[64 * 136];
  const int tid = threadIdx.x;
  const int n0 = blockIdx.x * 64;

  for (int m = 0; m < 2; ++m) {
    const float* x = m ? v : q;
    const unsigned short* WT = m ? WvT : WqT;
    unsigned short* o = m ? Vh : Qh;

    __syncthreads();
    #pragma unroll
    for (int p = 0; p < 4; ++p) {
      int f = p * 512 + tid;
      int i = f >> 5, c4 = f & 31;
      int n = n0 + i;
      float4 t = (n < NN) ? *(const float4*)&x[(size_t)n * DD + c4 * 4]
                          : float4{0.f, 0.f, 0.f, 0.f};
      ushort4v u = { f2bf(t.x), f2bf(t.y), f2bf(t.z), f2bf(t.w) };
      *(ushort4v*)&xl[i * 136 + c4 * 4] = u;
    }
    __syncthreads();

    const int lane = tid & 63, wid = tid >> 6;
    const int rg = wid & 3, cg = wid >> 2;
    const int lr = lane & 15, lg = lane >> 4;

    f32x4 acc0 = {0.f,0.f,0.f,0.f}, acc1 = {0.f,0.f,0.f,0.f};
    f32x4 acc2 = {0.f,0.f,0.f,0.f}, acc3 = {0.f,0.f,0.f,0.f};

    const unsigned short* Ab = &xl[(rg * 16 + lr) * 136];
    const unsigned short* B0 = &WT[(size_t)(cg * 64 +  0 + lr) * DD];
    const unsigned short* B1 = &WT[(size_t)(cg * 64 + 16 + lr) * DD];
    const unsigned short* B2 = &WT[(size_t)(cg * 64 + 32 + lr) * DD];
    const unsigned short* B3 = &WT[(size_t)(cg * 64 + 48 + lr) * DD];

    #pragma unroll
    for (int kk = 0; kk < 4; ++kk) {
      const int kof = kk * 32 + lg * 8;
      short8 a = *(const short8*)(Ab + kof);
      acc0 = __builtin_amdgcn_mfma_f32_16x16x32_bf16(a, *(const short8*)(B0 + kof), acc0, 0, 0, 0);
      acc1 = __builtin_amdgcn_mfma_f32_16x16x32_bf16(a, *(const short8*)(B1 + kof), acc1, 0, 0, 0);
      acc2 = __builtin_amdgcn_mfma_f32_16x16x32_bf16(a, *(const short8*)(B2 + kof), acc2, 0, 0, 0);
      acc3 = __builtin_amdgcn_mfma_f32_16x16x32_bf16(a, *(const short8*)(B3 + kof), acc3, 0, 0, 0);
    }

    const int r0 = rg * 16 + lg * 4;
    const int cb = cg * 64 + lr;
    #pragma unroll
    for (int r = 0; r < 4; ++r) {
      int n = n0 + r0 + r;
      if (n < NN) {
        unsigned short* orow = &o[(size_t)n * DD + cb];
        orow[ 0] = f2bf(acc0[r]);
        orow[16] = f2bf(acc1[r]);
        orow[32] = f2bf(acc2[r]);
        orow[48] = f2bf(acc3[r]);
      }
    }
  }
}

// ---------------------------------------------------------------------------
// Kernel 2: fused edge attention over DST-SORTED edges.
// Same structure as r2/r4, but edges come via perm (sorted by dst), and the
// final scatter is a wave-uniform segmented reduction: ONE atomicAdd per
// distinct dst per block (~5/block) instead of per edge (128/edge-row).
// No min-waves bound: let the allocator keep ILP (r4 lesson).
// ---------------------------------------------------------------------------
__global__ __launch_bounds__(512) void edge_attn_kernel(
    const float* __restrict__ k, const float* __restrict__ e,
    const int* __restrict__ src, const int* __restrict__ dst,
    const int* __restrict__ perm,
    const unsigned short* __restrict__ WkT,
    const unsigned short* __restrict__ Qh, const unsigned short* __restrict__ Vh,
    float* __restrict__ out)
{
  __shared__ __align__(16) unsigned short smem[2 * 64 * 136];  // 34816 B
  __shared__ int s_perm[64], s_src[64], s_dst[64];

  unsigned short* kke_l = smem;             // [64][136] bf16
  unsigned short* ke_l  = smem + 64 * 136;  // [64][136] bf16
  float* He = (float*)smem;                 // [64][132] f32 (33792 B)

  const int tid = threadIdx.x;
  const size_t e0 = (size_t)blockIdx.x * 64;

  if (tid < 64) {
    int pe = perm[e0 + tid];
    s_perm[tid] = pe;
    s_src[tid] = src[pe];
    s_dst[tid] = dst[pe];
  }
  __syncthreads();

  // ---- stage kke[i][c] = bf16(k[src_i][c] + e[perm_i][c]) ----
  #pragma unroll
  for (int p = 0; p < 4; ++p) {
    int f = p * 512 + tid;              // 2048 chunks of 4 floats
    int i = f >> 5, c4 = f & 31;
    float4 kv = *(const float4*)&k[(size_t)s_src[i] * DD + c4 * 4];
    float4 ev = *(const float4*)&e[(size_t)s_perm[i] * DD + c4 * 4];
    ushort4v o = { f2bf(kv.x + ev.x), f2bf(kv.y + ev.y),
                   f2bf(kv.z + ev.z), f2bf(kv.w + ev.w) };
    *(ushort4v*)&kke_l[i * 136 + c4 * 4] = o;
  }
  __syncthreads();

  // ---- phase 1: Ke = kke @ Wk via MFMA; B-frags from global WkT (L1-hot) ----
  {
    const int lane = tid & 63, wid = tid >> 6;
    const int rg = wid & 3, cg = wid >> 2;
    const int lr = lane & 15, lg = lane >> 4;

    f32x4 acc0 = {0.f,0.f,0.f,0.f}, acc1 = {0.f,0.f,0.f,0.f};
    f32x4 acc2 = {0.f,0.f,0.f,0.f}, acc3 = {0.f,0.f,0.f,0.f};

    const unsigned short* Ab = &kke_l[(rg * 16 + lr) * 136];
    const unsigned short* B0 = &WkT[(size_t)(cg * 64 +  0 + lr) * DD];
    const unsigned short* B1 = &WkT[(size_t)(cg * 64 + 16 + lr) * DD];
    const unsigned short* B2 = &WkT[(size_t)(cg * 64 + 32 + lr) * DD];
    const unsigned short* B3 = &WkT[(size_t)(cg * 64 + 48 + lr) * DD];

    #pragma unroll
    for (int kk = 0; kk < 4; ++kk) {
      const int kof = kk * 32 + lg * 8;
      short8 a = *(const short8*)(Ab + kof);
      acc0 = __builtin_amdgcn_mfma_f32_16x16x32_bf16(a, *(const short8*)(B0 + kof), acc0, 0, 0, 0);
      acc1 = __builtin_amdgcn_mfma_f32_16x16x32_bf16(a, *(const short8*)(B1 + kof), acc1, 0, 0, 0);
      acc2 = __builtin_amdgcn_mfma_f32_16x16x32_bf16(a, *(const short8*)(B2 + kof), acc2, 0, 0, 0);
      acc3 = __builtin_amdgcn_mfma_f32_16x16x32_bf16(a, *(const short8*)(B3 + kof), acc3, 0, 0, 0);
    }

    const int r0 = rg * 16 + lg * 4;
    const int cb = cg * 64 + lr;
    #pragma unroll
    for (int r = 0; r < 4; ++r) {
      ke_l[(r0 + r) * 136 + cb +  0] = f2bf(acc0[r]);
      ke_l[(r0 + r) * 136 + cb + 16] = f2bf(acc1[r]);
      ke_l[(r0 + r) * 136 + cb + 32] = f2bf(acc2[r]);
      ke_l[(r0 + r) * 136 + cb + 48] = f2bf(acc3[r]);
    }
  }
  __syncthreads();   // Ke ready; kke dead

  // ---- phase 2a: per (edge i, head h) scores + softmax ----
  const int i = tid >> 3, h = tid & 7;
  const int sn = s_src[i], dn = s_dst[i];

  float sc[8];
  {
    float Qr[16];
    ushort8v q0 = *(const ushort8v*)&Qh[(size_t)dn * DD + h * DKK];
    ushort8v q1 = *(const ushort8v*)&Qh[(size_t)dn * DD + h * DKK + 8];
    #pragma unroll
    for (int t = 0; t < 8; ++t) { Qr[t] = bf2f(q0[t]); Qr[8 + t] = bf2f(q1[t]); }

    #pragma unroll
    for (int g = 0; g < 8; ++g) {
      const ushort8v* kp = (const ushort8v*)&ke_l[i * 136 + g * DKK];
      ushort8v k0 = kp[0], k1 = kp[1];
      float a = 0.0f;
      #pragma unroll
      for (int t = 0; t < 8; ++t) a = fmaf(Qr[t], bf2f(k0[t]), a);
      #pragma unroll
      for (int t = 0; t < 8; ++t) a = fmaf(Qr[8 + t], bf2f(k1[t]), a);
      a *= 0.25f;
      sc[g] = (a >= 0.0f) ? a : 0.01f * a;
    }

    float mx = sc[0];
    #pragma unroll
    for (int g = 1; g < 8; ++g) mx = fmaxf(mx, sc[g]);
    float sum = 0.0f;
    #pragma unroll
    for (int g = 0; g < 8; ++g) { sc[g] = __expf(sc[g] - mx); sum += sc[g]; }
    float rs = 1.0f / sum;
    #pragma unroll
    for (int g = 0; g < 8; ++g) sc[g] *= rs;
  }
  __syncthreads();   // all ke_l reads done -> He may overwrite smem

  // ---- phase 2b: He = A @ Ve (bf16 V gather), stage into smem ----
  {
    float he[16];
    #pragma unroll
    for (int d = 0; d < 16; ++d) he[d] = 0.0f;
    #pragma unroll
    for (int g = 0; g < 8; ++g) {
      float a = sc[g];
      ushort8v v0 = *(const ushort8v*)&Vh[(size_t)sn * DD + g * DKK];
      ushort8v v1 = *(const ushort8v*)&Vh[(size_t)sn * DD + g * DKK + 8];
      #pragma unroll
      for (int t = 0; t < 8; ++t) {
        he[t]     = fmaf(a, bf2f(v0[t]), he[t]);
        he[8 + t] = fmaf(a, bf2f(v1[t]), he[8 + t]);
      }
    }
    #pragma unroll
    for (int d0 = 0; d0 < 4; ++d0) {
      float4 t = { he[d0 * 4], he[d0 * 4 + 1], he[d0 * 4 + 2], he[d0 * 4 + 3] };
      *(float4*)&He[i * 132 + h * DKK + d0 * 4] = t;
    }
  }
  __syncthreads();

  // ---- segmented reduce over dst-runs, one atomic per run per dword ----
  // 128 consecutive threads share one i2 -> run-head test is wave-uniform.
  for (int p = 0; p < 16; ++p) {
    int flat = p * 512 + tid;
    int i2 = flat >> 7, d = flat & 127;
    int dnn = s_dst[i2];
    bool head = (i2 == 0) || (s_dst[i2 - 1] != dnn);
    if (head) {
      float s = He[i2 * 132 + d];
      for (int j = i2 + 1; j < 64 && s_dst[j] == dnn; ++j)
        s += He[j * 132 + d];
      atomicAdd(&out[(size_t)dnn * DD + d], s);
    }
  }
}

// ---------------------------------------------------------------------------
extern "C" void kernel_launch(void* const* d_in, const int* in_sizes, int n_in,
                              void* d_out, int out_size, void* d_ws, size_t ws_size,
                              hipStream_t stream) {
  const float* q  = (const float*)d_in[0];
  const float* k  = (const float*)d_in[1];
  const float* v  = (const float*)d_in[2];
  const float* e  = (const float*)d_in[3];
  const int*   src = (const int*)d_in[4];
  const int*   dst = (const int*)d_in[5];
  const float* Wq = (const float*)d_in[6];
  const float* Wk = (const float*)d_in[7];
  const float* Wv = (const float*)d_in[8];

  float* out = (float*)d_out;
  char* wsb = (char*)d_ws;
  unsigned short* Qh  = (unsigned short*)wsb;                      // 12.8 MB
  unsigned short* Vh  = Qh + (size_t)NN * DD;                      // 12.8 MB
  unsigned short* WqT = Vh + (size_t)NN * DD;                      // 32 KB each
  unsigned short* WkT = WqT + DD * DD;
  unsigned short* WvT = WkT + DD * DD;
  int* cnt    = (int*)(WvT + DD * DD);                             // [NN]
  int* rowptr = cnt + NN;                                          // [NN+1]
  int* cur    = rowptr + NN + 1;                                   // [NN]
  int* perm   = cur + NN;                                          // [EE]

  hipMemsetAsync(d_out, 0, (size_t)NN * DD * sizeof(float), stream);
  hipMemsetAsync(cnt, 0, NN * sizeof(int), stream);
  hipMemsetAsync(cur, 0, NN * sizeof(int), stream);

  hist_kernel<<<(EE + 255) / 256, 256, 0, stream>>>(dst, cnt);
  scan_kernel<<<1, 1024, 0, stream>>>(cnt, rowptr);
  fill_kernel<<<(EE + 255) / 256, 256, 0, stream>>>(dst, rowptr, cur, perm);

  prep_w_kernel<<<3 * DD, DD, 0, stream>>>(Wq, Wk, Wv, WqT, WkT, WvT);
  node_proj_kernel<<<(NN + 63) / 64, 512, 0, stream>>>(q, v, WqT, WvT, Qh, Vh);
  edge_attn_kernel<<<EE / 64, 512, 0, stream>>>(k, e, src, dst, perm,
                                                WkT, Qh, Vh, out);
}

// Round 6
// 480.966 us; speedup vs baseline: 1.5973x; 1.5973x over previous
//
#include <hip/hip_runtime.h>
#include <hip/hip_bf16.h>
#include <math.h>

#define NN 50000
#define EE 800000
#define DD 128
#define HH 8
#define DKK 16

typedef __attribute__((ext_vector_type(8))) short short8;
typedef __attribute__((ext_vector_type(4))) float f32x4;
typedef __attribute__((ext_vector_type(4))) unsigned short ushort4v;
typedef __attribute__((ext_vector_type(8))) unsigned short ushort8v;

static __device__ __forceinline__ unsigned short f2bf(float x) {
  __hip_bfloat16 h = __float2bfloat16(x);   // RNE
  return *reinterpret_cast<unsigned short*>(&h);
}
static __device__ __forceinline__ float bf2f(unsigned short u) {
  return __uint_as_float(((unsigned int)u) << 16);
}

// ---------------------------------------------------------------------------
// Bucket-by-dst prep: histogram -> 3-dispatch coalesced scan -> perm fill.
// ---------------------------------------------------------------------------
__global__ __launch_bounds__(256) void hist_kernel(const int* __restrict__ dst,
                                                   int* __restrict__ cnt) {
  int i4 = blockIdx.x * 256 + threadIdx.x;
  if (i4 < EE / 4) {
    int4 d = *(const int4*)&dst[i4 * 4];
    atomicAdd(&cnt[d.x], 1);
    atomicAdd(&cnt[d.y], 1);
    atomicAdd(&cnt[d.z], 1);
    atomicAdd(&cnt[d.w], 1);
  }
}

#define SCAN_NB ((NN + 1023) / 1024)   // 49 chunks of 1024

__global__ __launch_bounds__(256) void scan1_kernel(const int* __restrict__ cnt,
                                                    int* __restrict__ bsum) {
  __shared__ int red[256];
  const int b = blockIdx.x, t = threadIdx.x;
  const int base = b * 1024 + t * 4;
  int s = 0;
  if (base + 3 < NN) {
    int4 v = *(const int4*)&cnt[base];
    s = v.x + v.y + v.z + v.w;
  } else {
    for (int j = 0; j < 4; ++j) if (base + j < NN) s += cnt[base + j];
  }
  red[t] = s;
  __syncthreads();
  for (int off = 1; off < 256; off <<= 1) {
    int v = (t >= off) ? red[t - off] : 0;
    __syncthreads();
    red[t] += v;
    __syncthreads();
  }
  if (t == 255) bsum[b] = red[255];
}

__global__ __launch_bounds__(64) void scan2_kernel(const int* __restrict__ bsum,
                                                   int* __restrict__ bpre) {
  int t = threadIdx.x;                      // one wave
  int v = (t < SCAN_NB) ? bsum[t] : 0;
  for (int off = 1; off < 64; off <<= 1) {
    int u = __shfl_up(v, off);
    if (t >= off) v += u;
  }
  if (t < SCAN_NB) bpre[t + 1] = v;
  if (t == 0) bpre[0] = 0;
}

__global__ __launch_bounds__(256) void scan3_kernel(const int* __restrict__ cnt,
                                                    const int* __restrict__ bpre,
                                                    int* __restrict__ rowptr) {
  __shared__ int red[256];
  const int b = blockIdx.x, t = threadIdx.x;
  const int base = b * 1024 + t * 4;
  int v0 = 0, v1 = 0, v2 = 0, v3 = 0;
  if (base + 3 < NN) {
    int4 v = *(const int4*)&cnt[base];
    v0 = v.x; v1 = v.y; v2 = v.z; v3 = v.w;
  } else {
    if (base + 0 < NN) v0 = cnt[base + 0];
    if (base + 1 < NN) v1 = cnt[base + 1];
    if (base + 2 < NN) v2 = cnt[base + 2];
    if (base + 3 < NN) v3 = cnt[base + 3];
  }
  red[t] = v0 + v1 + v2 + v3;
  __syncthreads();
  for (int off = 1; off < 256; off <<= 1) {
    int v = (t >= off) ? red[t - off] : 0;
    __syncthreads();
    red[t] += v;
    __syncthreads();
  }
  int r = bpre[b] + ((t == 0) ? 0 : red[t - 1]);   // exclusive within chunk
  if (base + 0 < NN) { rowptr[base + 0] = r; r += v0; }
  if (base + 1 < NN) { rowptr[base + 1] = r; r += v1; }
  if (base + 2 < NN) { rowptr[base + 2] = r; r += v2; }
  if (base + 3 < NN) { rowptr[base + 3] = r; }
}

__global__ __launch_bounds__(256) void fill_kernel(const int* __restrict__ dst,
                                                   const int* __restrict__ rowptr,
                                                   int* __restrict__ cur,
                                                   int* __restrict__ perm) {
  int i4 = blockIdx.x * 256 + threadIdx.x;
  if (i4 < EE / 4) {
    int4 dv = *(const int4*)&dst[i4 * 4];
    int d0 = dv.x, d1 = dv.y, d2 = dv.z, d3 = dv.w;
    int s0 = atomicAdd(&cur[d0], 1); perm[rowptr[d0] + s0] = i4 * 4 + 0;
    int s1 = atomicAdd(&cur[d1], 1); perm[rowptr[d1] + s1] = i4 * 4 + 1;
    int s2 = atomicAdd(&cur[d2], 1); perm[rowptr[d2] + s2] = i4 * 4 + 2;
    int s3 = atomicAdd(&cur[d3], 1); perm[rowptr[d3] + s3] = i4 * 4 + 3;
  }
}

// ---------------------------------------------------------------------------
// Prep: WT[j][c] = bf16(W[c][j]) for Wq, Wk, Wv (each 32KB bf16, L2-resident)
// ---------------------------------------------------------------------------
__global__ void prep_w_kernel(const float* __restrict__ Wq,
                              const float* __restrict__ Wk,
                              const float* __restrict__ Wv,
                              unsigned short* __restrict__ WqT,
                              unsigned short* __restrict__ WkT,
                              unsigned short* __restrict__ WvT) {
  int c = blockIdx.x & 127;
  int m = blockIdx.x >> 7;
  int j = threadIdx.x;
  const float* W = (m == 0) ? Wq : (m == 1) ? Wk : Wv;
  unsigned short* o = (m == 0) ? WqT : (m == 1) ? WkT : WvT;
  o[j * DD + c] = f2bf(W[c * DD + j]);
}

// ---------------------------------------------------------------------------
// Kernel 1: node projections via MFMA.  Qh = bf16(q @ Wq), Vh = bf16(v @ Wv).
// ---------------------------------------------------------------------------
__global__ __launch_bounds__(512) void node_proj_kernel(
    const float* __restrict__ q, const float* __restrict__ v,
    const unsigned short* __restrict__ WqT, const unsigned short* __restrict__ WvT,
    unsigned short* __restrict__ Qh, unsigned short* __restrict__ Vh)
{
  __shared__ __align__(16) unsigned short xl[64 * 136];
  const int tid = threadIdx.x;
  const int n0 = blockIdx.x * 64;

  for (int m = 0; m < 2; ++m) {
    const float* x = m ? v : q;
    const unsigned short* WT = m ? WvT : WqT;
    unsigned short* o = m ? Vh : Qh;

    __syncthreads();
    #pragma unroll
    for (int p = 0; p < 4; ++p) {
      int f = p * 512 + tid;
      int i = f >> 5, c4 = f & 31;
      int n = n0 + i;
      float4 t = (n < NN) ? *(const float4*)&x[(size_t)n * DD + c4 * 4]
                          : float4{0.f, 0.f, 0.f, 0.f};
      ushort4v u = { f2bf(t.x), f2bf(t.y), f2bf(t.z), f2bf(t.w) };
      *(ushort4v*)&xl[i * 136 + c4 * 4] = u;
    }
    __syncthreads();

    const int lane = tid & 63, wid = tid >> 6;
    const int rg = wid & 3, cg = wid >> 2;
    const int lr = lane & 15, lg = lane >> 4;

    f32x4 acc0 = {0.f,0.f,0.f,0.f}, acc1 = {0.f,0.f,0.f,0.f};
    f32x4 acc2 = {0.f,0.f,0.f,0.f}, acc3 = {0.f,0.f,0.f,0.f};

    const unsigned short* Ab = &xl[(rg * 16 + lr) * 136];
    const unsigned short* B0 = &WT[(size_t)(cg * 64 +  0 + lr) * DD];
    const unsigned short* B1 = &WT[(size_t)(cg * 64 + 16 + lr) * DD];
    const unsigned short* B2 = &WT[(size_t)(cg * 64 + 32 + lr) * DD];
    const unsigned short* B3 = &WT[(size_t)(cg * 64 + 48 + lr) * DD];

    #pragma unroll
    for (int kk = 0; kk < 4; ++kk) {
      const int kof = kk * 32 + lg * 8;
      short8 a = *(const short8*)(Ab + kof);
      acc0 = __builtin_amdgcn_mfma_f32_16x16x32_bf16(a, *(const short8*)(B0 + kof), acc0, 0, 0, 0);
      acc1 = __builtin_amdgcn_mfma_f32_16x16x32_bf16(a, *(const short8*)(B1 + kof), acc1, 0, 0, 0);
      acc2 = __builtin_amdgcn_mfma_f32_16x16x32_bf16(a, *(const short8*)(B2 + kof), acc2, 0, 0, 0);
      acc3 = __builtin_amdgcn_mfma_f32_16x16x32_bf16(a, *(const short8*)(B3 + kof), acc3, 0, 0, 0);
    }

    const int r0 = rg * 16 + lg * 4;
    const int cb = cg * 64 + lr;
    #pragma unroll
    for (int r = 0; r < 4; ++r) {
      int n = n0 + r0 + r;
      if (n < NN) {
        unsigned short* orow = &o[(size_t)n * DD + cb];
        orow[ 0] = f2bf(acc0[r]);
        orow[16] = f2bf(acc1[r]);
        orow[32] = f2bf(acc2[r]);
        orow[48] = f2bf(acc3[r]);
      }
    }
  }
}

// ---------------------------------------------------------------------------
// Kernel 2: fused edge attention over DST-SORTED edges.
// Tail = parallel chunked flush: 4 chunks x 128 d-lanes; each thread
// register-accumulates 16 sorted edges, flushing on dst change (~2 atomics).
// ---------------------------------------------------------------------------
__global__ __launch_bounds__(512) void edge_attn_kernel(
    const float* __restrict__ k, const float* __restrict__ e,
    const int* __restrict__ src, const int* __restrict__ dst,
    const int* __restrict__ perm,
    const unsigned short* __restrict__ WkT,
    const unsigned short* __restrict__ Qh, const unsigned short* __restrict__ Vh,
    float* __restrict__ out)
{
  __shared__ __align__(16) unsigned short smem[2 * 64 * 136];  // 34816 B
  __shared__ int s_perm[64], s_src[64], s_dst[64];

  unsigned short* kke_l = smem;             // [64][136] bf16
  unsigned short* ke_l  = smem + 64 * 136;  // [64][136] bf16
  float* He = (float*)smem;                 // [64][132] f32 (33792 B)

  const int tid = threadIdx.x;
  const size_t e0 = (size_t)blockIdx.x * 64;

  if (tid < 64) {
    int pe = perm[e0 + tid];
    s_perm[tid] = pe;
    s_src[tid] = src[pe];
    s_dst[tid] = dst[pe];
  }
  __syncthreads();

  // ---- stage kke[i][c] = bf16(k[src_i][c] + e[perm_i][c]) ----
  #pragma unroll
  for (int p = 0; p < 4; ++p) {
    int f = p * 512 + tid;              // 2048 chunks of 4 floats
    int i = f >> 5, c4 = f & 31;
    float4 kv = *(const float4*)&k[(size_t)s_src[i] * DD + c4 * 4];
    float4 ev = *(const float4*)&e[(size_t)s_perm[i] * DD + c4 * 4];
    ushort4v o = { f2bf(kv.x + ev.x), f2bf(kv.y + ev.y),
                   f2bf(kv.z + ev.z), f2bf(kv.w + ev.w) };
    *(ushort4v*)&kke_l[i * 136 + c4 * 4] = o;
  }
  __syncthreads();

  // ---- phase 1: Ke = kke @ Wk via MFMA; B-frags from global WkT (L1-hot) ----
  {
    const int lane = tid & 63, wid = tid >> 6;
    const int rg = wid & 3, cg = wid >> 2;
    const int lr = lane & 15, lg = lane >> 4;

    f32x4 acc0 = {0.f,0.f,0.f,0.f}, acc1 = {0.f,0.f,0.f,0.f};
    f32x4 acc2 = {0.f,0.f,0.f,0.f}, acc3 = {0.f,0.f,0.f,0.f};

    const unsigned short* Ab = &kke_l[(rg * 16 + lr) * 136];
    const unsigned short* B0 = &WkT[(size_t)(cg * 64 +  0 + lr) * DD];
    const unsigned short* B1 = &WkT[(size_t)(cg * 64 + 16 + lr) * DD];
    const unsigned short* B2 = &WkT[(size_t)(cg * 64 + 32 + lr) * DD];
    const unsigned short* B3 = &WkT[(size_t)(cg * 64 + 48 + lr) * DD];

    #pragma unroll
    for (int kk = 0; kk < 4; ++kk) {
      const int kof = kk * 32 + lg * 8;
      short8 a = *(const short8*)(Ab + kof);
      acc0 = __builtin_amdgcn_mfma_f32_16x16x32_bf16(a, *(const short8*)(B0 + kof), acc0, 0, 0, 0);
      acc1 = __builtin_amdgcn_mfma_f32_16x16x32_bf16(a, *(const short8*)(B1 + kof), acc1, 0, 0, 0);
      acc2 = __builtin_amdgcn_mfma_f32_16x16x32_bf16(a, *(const short8*)(B2 + kof), acc2, 0, 0, 0);
      acc3 = __builtin_amdgcn_mfma_f32_16x16x32_bf16(a, *(const short8*)(B3 + kof), acc3, 0, 0, 0);
    }

    const int r0 = rg * 16 + lg * 4;
    const int cb = cg * 64 + lr;
    #pragma unroll
    for (int r = 0; r < 4; ++r) {
      ke_l[(r0 + r) * 136 + cb +  0] = f2bf(acc0[r]);
      ke_l[(r0 + r) * 136 + cb + 16] = f2bf(acc1[r]);
      ke_l[(r0 + r) * 136 + cb + 32] = f2bf(acc2[r]);
      ke_l[(r0 + r) * 136 + cb + 48] = f2bf(acc3[r]);
    }
  }
  __syncthreads();   // Ke ready; kke dead

  // ---- phase 2a: per (edge i, head h) scores + softmax ----
  const int i = tid >> 3, h = tid & 7;
  const int sn = s_src[i], dn = s_dst[i];

  float sc[8];
  {
    float Qr[16];
    ushort8v q0 = *(const ushort8v*)&Qh[(size_t)dn * DD + h * DKK];
    ushort8v q1 = *(const ushort8v*)&Qh[(size_t)dn * DD + h * DKK + 8];
    #pragma unroll
    for (int t = 0; t < 8; ++t) { Qr[t] = bf2f(q0[t]); Qr[8 + t] = bf2f(q1[t]); }

    #pragma unroll
    for (int g = 0; g < 8; ++g) {
      const ushort8v* kp = (const ushort8v*)&ke_l[i * 136 + g * DKK];
      ushort8v k0 = kp[0], k1 = kp[1];
      float a = 0.0f;
      #pragma unroll
      for (int t = 0; t < 8; ++t) a = fmaf(Qr[t], bf2f(k0[t]), a);
      #pragma unroll
      for (int t = 0; t < 8; ++t) a = fmaf(Qr[8 + t], bf2f(k1[t]), a);
      a *= 0.25f;
      sc[g] = (a >= 0.0f) ? a : 0.01f * a;
    }

    float mx = sc[0];
    #pragma unroll
    for (int g = 1; g < 8; ++g) mx = fmaxf(mx, sc[g]);
    float sum = 0.0f;
    #pragma unroll
    for (int g = 0; g < 8; ++g) { sc[g] = __expf(sc[g] - mx); sum += sc[g]; }
    float rs = 1.0f / sum;
    #pragma unroll
    for (int g = 0; g < 8; ++g) sc[g] *= rs;
  }
  __syncthreads();   // all ke_l reads done -> He may overwrite smem

  // ---- phase 2b: He = A @ Ve (bf16 V gather), stage into smem ----
  {
    float he[16];
    #pragma unroll
    for (int d = 0; d < 16; ++d) he[d] = 0.0f;
    #pragma unroll
    for (int g = 0; g < 8; ++g) {
      float a = sc[g];
      ushort8v v0 = *(const ushort8v*)&Vh[(size_t)sn * DD + g * DKK];
      ushort8v v1 = *(const ushort8v*)&Vh[(size_t)sn * DD + g * DKK + 8];
      #pragma unroll
      for (int t = 0; t < 8; ++t) {
        he[t]     = fmaf(a, bf2f(v0[t]), he[t]);
        he[8 + t] = fmaf(a, bf2f(v1[t]), he[8 + t]);
      }
    }
    #pragma unroll
    for (int d0 = 0; d0 < 4; ++d0) {
      float4 t = { he[d0 * 4], he[d0 * 4 + 1], he[d0 * 4 + 2], he[d0 * 4 + 3] };
      *(float4*)&He[i * 132 + h * DKK + d0 * 4] = t;
    }
  }
  __syncthreads();

  // ---- parallel chunked flush: 4 chunks x 128 d, flush on dst change ----
  {
    const int c  = tid >> 7;          // chunk 0..3 -> edges [c*16, c*16+16)
    const int d  = tid & 127;
    const int i2base = c * 16;
    float s = 0.0f;
    int curd = s_dst[i2base];
    #pragma unroll
    for (int j = 0; j < 16; ++j) {
      int i2 = i2base + j;
      int dn2 = s_dst[i2];
      if (dn2 != curd) {
        atomicAdd(&out[(size_t)curd * DD + d], s);
        s = 0.0f;
        curd = dn2;
      }
      s += He[i2 * 132 + d];
    }
    atomicAdd(&out[(size_t)curd * DD + d], s);
  }
}

// ---------------------------------------------------------------------------
extern "C" void kernel_launch(void* const* d_in, const int* in_sizes, int n_in,
                              void* d_out, int out_size, void* d_ws, size_t ws_size,
                              hipStream_t stream) {
  const float* q  = (const float*)d_in[0];
  const float* k  = (const float*)d_in[1];
  const float* v  = (const float*)d_in[2];
  const float* e  = (const float*)d_in[3];
  const int*   src = (const int*)d_in[4];
  const int*   dst = (const int*)d_in[5];
  const float* Wq = (const float*)d_in[6];
  const float* Wk = (const float*)d_in[7];
  const float* Wv = (const float*)d_in[8];

  float* out = (float*)d_out;
  char* wsb = (char*)d_ws;
  unsigned short* Qh  = (unsigned short*)wsb;                      // 12.8 MB
  unsigned short* Vh  = Qh + (size_t)NN * DD;                      // 12.8 MB
  unsigned short* WqT = Vh + (size_t)NN * DD;                      // 32 KB each
  unsigned short* WkT = WqT + DD * DD;
  unsigned short* WvT = WkT + DD * DD;
  int* cnt    = (int*)(WvT + DD * DD);                             // [NN]
  int* cur    = cnt + NN;                                          // [NN] (adjacent: one memset)
  int* rowptr = cur + NN;                                          // [NN+1]
  int* bsum   = rowptr + NN + 1;                                   // [64]
  int* bpre   = bsum + 64;                                         // [64]
  int* perm   = bpre + 64;                                         // [EE]

  hipMemsetAsync(d_out, 0, (size_t)NN * DD * sizeof(float), stream);
  hipMemsetAsync(cnt, 0, 2 * NN * sizeof(int), stream);            // cnt + cur

  hist_kernel <<<(EE / 4 + 255) / 256, 256, 0, stream>>>(dst, cnt);
  scan1_kernel<<<SCAN_NB, 256, 0, stream>>>(cnt, bsum);
  scan2_kernel<<<1, 64, 0, stream>>>(bsum, bpre);
  scan3_kernel<<<SCAN_NB, 256, 0, stream>>>(cnt, bpre, rowptr);
  fill_kernel <<<(EE / 4 + 255) / 256, 256, 0, stream>>>(dst, rowptr, cur, perm);

  prep_w_kernel<<<3 * DD, DD, 0, stream>>>(Wq, Wk, Wv, WqT, WkT, WvT);
  node_proj_kernel<<<(NN + 63) / 64, 512, 0, stream>>>(q, v, WqT, WvT, Qh, Vh);
  edge_attn_kernel<<<EE / 64, 512, 0, stream>>>(k, e, src, dst, perm,
                                                WkT, Qh, Vh, out);
}

// Round 7
// 400.755 us; speedup vs baseline: 1.9170x; 1.2001x over previous
//
#include <hip/hip_runtime.h>
#include <hip/hip_bf16.h>
#include <math.h>

#define NN 50000
#define EE 800000
#define DD 128
#define HH 8
#define DKK 16

typedef __attribute__((ext_vector_type(8))) short short8;
typedef __attribute__((ext_vector_type(4))) float f32x4;
typedef __attribute__((ext_vector_type(4))) unsigned short ushort4v;
typedef __attribute__((ext_vector_type(8))) unsigned short ushort8v;

static __device__ __forceinline__ unsigned short f2bf(float x) {
  __hip_bfloat16 h = __float2bfloat16(x);   // RNE
  return *reinterpret_cast<unsigned short*>(&h);
}
static __device__ __forceinline__ float bf2f(unsigned short u) {
  return __uint_as_float(((unsigned int)u) << 16);
}

// ---------------------------------------------------------------------------
// Bucket-by-dst prep: histogram -> 3-dispatch coalesced scan -> perm fill.
// ---------------------------------------------------------------------------
__global__ __launch_bounds__(256) void hist_kernel(const int* __restrict__ dst,
                                                   int* __restrict__ cnt) {
  int i4 = blockIdx.x * 256 + threadIdx.x;
  if (i4 < EE / 4) {
    int4 d = *(const int4*)&dst[i4 * 4];
    atomicAdd(&cnt[d.x], 1);
    atomicAdd(&cnt[d.y], 1);
    atomicAdd(&cnt[d.z], 1);
    atomicAdd(&cnt[d.w], 1);
  }
}

#define SCAN_NB ((NN + 1023) / 1024)   // 49 chunks of 1024

__global__ __launch_bounds__(256) void scan1_kernel(const int* __restrict__ cnt,
                                                    int* __restrict__ bsum) {
  __shared__ int red[256];
  const int b = blockIdx.x, t = threadIdx.x;
  const int base = b * 1024 + t * 4;
  int s = 0;
  if (base + 3 < NN) {
    int4 v = *(const int4*)&cnt[base];
    s = v.x + v.y + v.z + v.w;
  } else {
    for (int j = 0; j < 4; ++j) if (base + j < NN) s += cnt[base + j];
  }
  red[t] = s;
  __syncthreads();
  for (int off = 1; off < 256; off <<= 1) {
    int v = (t >= off) ? red[t - off] : 0;
    __syncthreads();
    red[t] += v;
    __syncthreads();
  }
  if (t == 255) bsum[b] = red[255];
}

__global__ __launch_bounds__(64) void scan2_kernel(const int* __restrict__ bsum,
                                                   int* __restrict__ bpre) {
  int t = threadIdx.x;                      // one wave
  int v = (t < SCAN_NB) ? bsum[t] : 0;
  for (int off = 1; off < 64; off <<= 1) {
    int u = __shfl_up(v, off);
    if (t >= off) v += u;
  }
  if (t < SCAN_NB) bpre[t + 1] = v;
  if (t == 0) bpre[0] = 0;
}

__global__ __launch_bounds__(256) void scan3_kernel(const int* __restrict__ cnt,
                                                    const int* __restrict__ bpre,
                                                    int* __restrict__ rowptr) {
  __shared__ int red[256];
  const int b = blockIdx.x, t = threadIdx.x;
  const int base = b * 1024 + t * 4;
  int v0 = 0, v1 = 0, v2 = 0, v3 = 0;
  if (base + 3 < NN) {
    int4 v = *(const int4*)&cnt[base];
    v0 = v.x; v1 = v.y; v2 = v.z; v3 = v.w;
  } else {
    if (base + 0 < NN) v0 = cnt[base + 0];
    if (base + 1 < NN) v1 = cnt[base + 1];
    if (base + 2 < NN) v2 = cnt[base + 2];
    if (base + 3 < NN) v3 = cnt[base + 3];
  }
  red[t] = v0 + v1 + v2 + v3;
  __syncthreads();
  for (int off = 1; off < 256; off <<= 1) {
    int v = (t >= off) ? red[t - off] : 0;
    __syncthreads();
    red[t] += v;
    __syncthreads();
  }
  int r = bpre[b] + ((t == 0) ? 0 : red[t - 1]);   // exclusive within chunk
  if (base + 0 < NN) { rowptr[base + 0] = r; r += v0; }
  if (base + 1 < NN) { rowptr[base + 1] = r; r += v1; }
  if (base + 2 < NN) { rowptr[base + 2] = r; r += v2; }
  if (base + 3 < NN) { rowptr[base + 3] = r; }
}

__global__ __launch_bounds__(256) void fill_kernel(const int* __restrict__ dst,
                                                   const int* __restrict__ rowptr,
                                                   int* __restrict__ cur,
                                                   int* __restrict__ perm) {
  int i4 = blockIdx.x * 256 + threadIdx.x;
  if (i4 < EE / 4) {
    int4 dv = *(const int4*)&dst[i4 * 4];
    int d0 = dv.x, d1 = dv.y, d2 = dv.z, d3 = dv.w;
    int s0 = atomicAdd(&cur[d0], 1); perm[rowptr[d0] + s0] = i4 * 4 + 0;
    int s1 = atomicAdd(&cur[d1], 1); perm[rowptr[d1] + s1] = i4 * 4 + 1;
    int s2 = atomicAdd(&cur[d2], 1); perm[rowptr[d2] + s2] = i4 * 4 + 2;
    int s3 = atomicAdd(&cur[d3], 1); perm[rowptr[d3] + s3] = i4 * 4 + 3;
  }
}

// ---------------------------------------------------------------------------
// Prep: WT[j][c] = bf16(W[c][j]);  kh = bf16(k)
// ---------------------------------------------------------------------------
__global__ void prep_w_kernel(const float* __restrict__ Wq,
                              const float* __restrict__ Wk,
                              const float* __restrict__ Wv,
                              unsigned short* __restrict__ WqT,
                              unsigned short* __restrict__ WkT,
                              unsigned short* __restrict__ WvT) {
  int c = blockIdx.x & 127;
  int m = blockIdx.x >> 7;
  int j = threadIdx.x;
  const float* W = (m == 0) ? Wq : (m == 1) ? Wk : Wv;
  unsigned short* o = (m == 0) ? WqT : (m == 1) ? WkT : WvT;
  o[j * DD + c] = f2bf(W[c * DD + j]);
}

__global__ __launch_bounds__(256) void conv_k_kernel(const float* __restrict__ k,
                                                     unsigned short* __restrict__ kh) {
  int i8 = blockIdx.x * 256 + threadIdx.x;    // 8-elem chunk
  if (i8 < NN * DD / 8) {
    float4 a = *(const float4*)&k[(size_t)i8 * 8];
    float4 b = *(const float4*)&k[(size_t)i8 * 8 + 4];
    ushort8v o = { f2bf(a.x), f2bf(a.y), f2bf(a.z), f2bf(a.w),
                   f2bf(b.x), f2bf(b.y), f2bf(b.z), f2bf(b.w) };
    *(ushort8v*)&kh[(size_t)i8 * 8] = o;
  }
}

// ---------------------------------------------------------------------------
// Kernel 1: node projections via MFMA.  Qh = bf16(q @ Wq), Vh = bf16(v @ Wv).
// ---------------------------------------------------------------------------
__global__ __launch_bounds__(512) void node_proj_kernel(
    const float* __restrict__ q, const float* __restrict__ v,
    const unsigned short* __restrict__ WqT, const unsigned short* __restrict__ WvT,
    unsigned short* __restrict__ Qh, unsigned short* __restrict__ Vh)
{
  __shared__ __align__(16) unsigned short xl[64 * 136];
  const int tid = threadIdx.x;
  const int n0 = blockIdx.x * 64;

  for (int m = 0; m < 2; ++m) {
    const float* x = m ? v : q;
    const unsigned short* WT = m ? WvT : WqT;
    unsigned short* o = m ? Vh : Qh;

    __syncthreads();
    #pragma unroll
    for (int p = 0; p < 4; ++p) {
      int f = p * 512 + tid;
      int i = f >> 5, c4 = f & 31;
      int n = n0 + i;
      float4 t = (n < NN) ? *(const float4*)&x[(size_t)n * DD + c4 * 4]
                          : float4{0.f, 0.f, 0.f, 0.f};
      ushort4v u = { f2bf(t.x), f2bf(t.y), f2bf(t.z), f2bf(t.w) };
      *(ushort4v*)&xl[i * 136 + c4 * 4] = u;
    }
    __syncthreads();

    const int lane = tid & 63, wid = tid >> 6;
    const int rg = wid & 3, cg = wid >> 2;
    const int lr = lane & 15, lg = lane >> 4;

    f32x4 acc0 = {0.f,0.f,0.f,0.f}, acc1 = {0.f,0.f,0.f,0.f};
    f32x4 acc2 = {0.f,0.f,0.f,0.f}, acc3 = {0.f,0.f,0.f,0.f};

    const unsigned short* Ab = &xl[(rg * 16 + lr) * 136];
    const unsigned short* B0 = &WT[(size_t)(cg * 64 +  0 + lr) * DD];
    const unsigned short* B1 = &WT[(size_t)(cg * 64 + 16 + lr) * DD];
    const unsigned short* B2 = &WT[(size_t)(cg * 64 + 32 + lr) * DD];
    const unsigned short* B3 = &WT[(size_t)(cg * 64 + 48 + lr) * DD];

    #pragma unroll
    for (int kk = 0; kk < 4; ++kk) {
      const int kof = kk * 32 + lg * 8;
      short8 a = *(const short8*)(Ab + kof);
      acc0 = __builtin_amdgcn_mfma_f32_16x16x32_bf16(a, *(const short8*)(B0 + kof), acc0, 0, 0, 0);
      acc1 = __builtin_amdgcn_mfma_f32_16x16x32_bf16(a, *(const short8*)(B1 + kof), acc1, 0, 0, 0);
      acc2 = __builtin_amdgcn_mfma_f32_16x16x32_bf16(a, *(const short8*)(B2 + kof), acc2, 0, 0, 0);
      acc3 = __builtin_amdgcn_mfma_f32_16x16x32_bf16(a, *(const short8*)(B3 + kof), acc3, 0, 0, 0);
    }

    const int r0 = rg * 16 + lg * 4;
    const int cb = cg * 64 + lr;
    #pragma unroll
    for (int r = 0; r < 4; ++r) {
      int n = n0 + r0 + r;
      if (n < NN) {
        unsigned short* orow = &o[(size_t)n * DD + cb];
        orow[ 0] = f2bf(acc0[r]);
        orow[16] = f2bf(acc1[r]);
        orow[32] = f2bf(acc2[r]);
        orow[48] = f2bf(acc3[r]);
      }
    }
  }
}

// ---------------------------------------------------------------------------
// Kernel 2: fused edge attention, 128 dst-sorted edges/block, 512 threads.
// LDS ~71KB -> 2 blocks/CU. Each thread owns (edge i, head h) AND
// (edge i+64, head h). Q gather issued early (hidden under stage+MFMA).
// ---------------------------------------------------------------------------
__global__ __launch_bounds__(512, 4) void edge_attn_kernel(
    const unsigned short* __restrict__ kh, const float* __restrict__ e,
    const int* __restrict__ src, const int* __restrict__ dst,
    const int* __restrict__ perm,
    const unsigned short* __restrict__ WkT,
    const unsigned short* __restrict__ Qh, const unsigned short* __restrict__ Vh,
    float* __restrict__ out)
{
  __shared__ __align__(16) unsigned short smem[2 * 128 * 136];  // 69632 B
  __shared__ int s_perm[128], s_src[128], s_dst[128];

  unsigned short* kke_l = smem;              // [128][136] bf16
  unsigned short* ke_l  = smem + 128 * 136;  // [128][136] bf16
  float* He = (float*)smem;                  // [128][132] f32 (67584 B)

  const int tid = threadIdx.x;
  const size_t e0 = (size_t)blockIdx.x * 128;

  if (tid < 128) {
    int pe = perm[e0 + tid];
    s_perm[tid] = pe;
    s_src[tid] = src[pe];
    s_dst[tid] = dst[pe];
  }
  __syncthreads();

  // ---- early-issue Q gather for this thread's two (edge, head) slots ----
  const int i0 = tid >> 3, i1 = i0 + 64, h = tid & 7;
  const int sn0 = s_src[i0], dn0 = s_dst[i0];
  const int sn1 = s_src[i1], dn1 = s_dst[i1];
  ushort8v qa0 = *(const ushort8v*)&Qh[(size_t)dn0 * DD + h * DKK];
  ushort8v qa1 = *(const ushort8v*)&Qh[(size_t)dn0 * DD + h * DKK + 8];
  ushort8v qb0 = *(const ushort8v*)&Qh[(size_t)dn1 * DD + h * DKK];
  ushort8v qb1 = *(const ushort8v*)&Qh[(size_t)dn1 * DD + h * DKK + 8];

  // ---- stage kke[i][c] = bf16(kh[src_i][c] + e[perm_i][c]) ----
  #pragma unroll
  for (int p = 0; p < 4; ++p) {
    int f = p * 512 + tid;              // 2048 chunks of 8 cols
    int i2 = f >> 4, c8 = f & 15;
    ushort8v kv = *(const ushort8v*)&kh[(size_t)s_src[i2] * DD + c8 * 8];
    float4 ea = *(const float4*)&e[(size_t)s_perm[i2] * DD + c8 * 8];
    float4 eb = *(const float4*)&e[(size_t)s_perm[i2] * DD + c8 * 8 + 4];
    ushort8v o;
    o[0] = f2bf(bf2f(kv[0]) + ea.x);
    o[1] = f2bf(bf2f(kv[1]) + ea.y);
    o[2] = f2bf(bf2f(kv[2]) + ea.z);
    o[3] = f2bf(bf2f(kv[3]) + ea.w);
    o[4] = f2bf(bf2f(kv[4]) + eb.x);
    o[5] = f2bf(bf2f(kv[5]) + eb.y);
    o[6] = f2bf(bf2f(kv[6]) + eb.z);
    o[7] = f2bf(bf2f(kv[7]) + eb.w);
    *(ushort8v*)&kke_l[i2 * 136 + c8 * 8] = o;
  }
  __syncthreads();

  // ---- phase 1: Ke = kke @ Wk. 8 waves x 2 row-groups (shared B-frags) ----
  {
    const int lane = tid & 63, wid = tid >> 6;
    const int rgA = wid & 3, rgB = (wid & 3) + 4, cg = wid >> 2;
    const int lr = lane & 15, lg = lane >> 4;

    f32x4 aA0 = {0.f,0.f,0.f,0.f}, aA1 = {0.f,0.f,0.f,0.f};
    f32x4 aA2 = {0.f,0.f,0.f,0.f}, aA3 = {0.f,0.f,0.f,0.f};
    f32x4 aB0 = {0.f,0.f,0.f,0.f}, aB1 = {0.f,0.f,0.f,0.f};
    f32x4 aB2 = {0.f,0.f,0.f,0.f}, aB3 = {0.f,0.f,0.f,0.f};

    const unsigned short* AbA = &kke_l[(rgA * 16 + lr) * 136];
    const unsigned short* AbB = &kke_l[(rgB * 16 + lr) * 136];
    const unsigned short* B0 = &WkT[(size_t)(cg * 64 +  0 + lr) * DD];
    const unsigned short* B1 = &WkT[(size_t)(cg * 64 + 16 + lr) * DD];
    const unsigned short* B2 = &WkT[(size_t)(cg * 64 + 32 + lr) * DD];
    const unsigned short* B3 = &WkT[(size_t)(cg * 64 + 48 + lr) * DD];

    #pragma unroll
    for (int kk = 0; kk < 4; ++kk) {
      const int kof = kk * 32 + lg * 8;
      short8 b0 = *(const short8*)(B0 + kof);
      short8 b1 = *(const short8*)(B1 + kof);
      short8 b2 = *(const short8*)(B2 + kof);
      short8 b3 = *(const short8*)(B3 + kof);
      short8 fA = *(const short8*)(AbA + kof);
      short8 fB = *(const short8*)(AbB + kof);
      aA0 = __builtin_amdgcn_mfma_f32_16x16x32_bf16(fA, b0, aA0, 0, 0, 0);
      aA1 = __builtin_amdgcn_mfma_f32_16x16x32_bf16(fA, b1, aA1, 0, 0, 0);
      aA2 = __builtin_amdgcn_mfma_f32_16x16x32_bf16(fA, b2, aA2, 0, 0, 0);
      aA3 = __builtin_amdgcn_mfma_f32_16x16x32_bf16(fA, b3, aA3, 0, 0, 0);
      aB0 = __builtin_amdgcn_mfma_f32_16x16x32_bf16(fB, b0, aB0, 0, 0, 0);
      aB1 = __builtin_amdgcn_mfma_f32_16x16x32_bf16(fB, b1, aB1, 0, 0, 0);
      aB2 = __builtin_amdgcn_mfma_f32_16x16x32_bf16(fB, b2, aB2, 0, 0, 0);
      aB3 = __builtin_amdgcn_mfma_f32_16x16x32_bf16(fB, b3, aB3, 0, 0, 0);
    }

    const int rA = rgA * 16 + lg * 4;
    const int rB = rgB * 16 + lg * 4;
    const int cb = cg * 64 + lr;
    #pragma unroll
    for (int r = 0; r < 4; ++r) {
      ke_l[(rA + r) * 136 + cb +  0] = f2bf(aA0[r]);
      ke_l[(rA + r) * 136 + cb + 16] = f2bf(aA1[r]);
      ke_l[(rA + r) * 136 + cb + 32] = f2bf(aA2[r]);
      ke_l[(rA + r) * 136 + cb + 48] = f2bf(aA3[r]);
      ke_l[(rB + r) * 136 + cb +  0] = f2bf(aB0[r]);
      ke_l[(rB + r) * 136 + cb + 16] = f2bf(aB1[r]);
      ke_l[(rB + r) * 136 + cb + 32] = f2bf(aB2[r]);
      ke_l[(rB + r) * 136 + cb + 48] = f2bf(aB3[r]);
    }
  }
  __syncthreads();   // Ke ready

  // ---- phase 2a: scores + softmax for both edges (reads ke_l + Q regs) ----
  float sc0[8], sc1[8];
  {
    #pragma unroll
    for (int g = 0; g < 8; ++g) {
      const ushort8v* kp = (const ushort8v*)&ke_l[i0 * 136 + g * DKK];
      ushort8v k0 = kp[0], k1 = kp[1];
      float a = 0.0f;
      #pragma unroll
      for (int t = 0; t < 8; ++t) a = fmaf(bf2f(qa0[t]), bf2f(k0[t]), a);
      #pragma unroll
      for (int t = 0; t < 8; ++t) a = fmaf(bf2f(qa1[t]), bf2f(k1[t]), a);
      a *= 0.25f;
      sc0[g] = (a >= 0.0f) ? a : 0.01f * a;
    }
    #pragma unroll
    for (int g = 0; g < 8; ++g) {
      const ushort8v* kp = (const ushort8v*)&ke_l[i1 * 136 + g * DKK];
      ushort8v k0 = kp[0], k1 = kp[1];
      float a = 0.0f;
      #pragma unroll
      for (int t = 0; t < 8; ++t) a = fmaf(bf2f(qb0[t]), bf2f(k0[t]), a);
      #pragma unroll
      for (int t = 0; t < 8; ++t) a = fmaf(bf2f(qb1[t]), bf2f(k1[t]), a);
      a *= 0.25f;
      sc1[g] = (a >= 0.0f) ? a : 0.01f * a;
    }
    float mx0 = sc0[0], mx1 = sc1[0];
    #pragma unroll
    for (int g = 1; g < 8; ++g) { mx0 = fmaxf(mx0, sc0[g]); mx1 = fmaxf(mx1, sc1[g]); }
    float su0 = 0.0f, su1 = 0.0f;
    #pragma unroll
    for (int g = 0; g < 8; ++g) {
      sc0[g] = __expf(sc0[g] - mx0); su0 += sc0[g];
      sc1[g] = __expf(sc1[g] - mx1); su1 += sc1[g];
    }
    float r0 = 1.0f / su0, r1 = 1.0f / su1;
    #pragma unroll
    for (int g = 0; g < 8; ++g) { sc0[g] *= r0; sc1[g] *= r1; }
  }
  __syncthreads();   // all ke_l reads done -> He may overwrite smem

  // ---- phase 2b: He = A @ Ve (bf16 V gather); edge0 then edge1 ----
  {
    float he[16];
    #pragma unroll
    for (int d = 0; d < 16; ++d) he[d] = 0.0f;
    #pragma unroll
    for (int g = 0; g < 8; ++g) {
      float a = sc0[g];
      ushort8v v0 = *(const ushort8v*)&Vh[(size_t)sn0 * DD + g * DKK];
      ushort8v v1 = *(const ushort8v*)&Vh[(size_t)sn0 * DD + g * DKK + 8];
      #pragma unroll
      for (int t = 0; t < 8; ++t) {
        he[t]     = fmaf(a, bf2f(v0[t]), he[t]);
        he[8 + t] = fmaf(a, bf2f(v1[t]), he[8 + t]);
      }
    }
    #pragma unroll
    for (int d0 = 0; d0 < 4; ++d0) {
      float4 t = { he[d0 * 4], he[d0 * 4 + 1], he[d0 * 4 + 2], he[d0 * 4 + 3] };
      *(float4*)&He[i0 * 132 + h * DKK + d0 * 4] = t;
    }
    #pragma unroll
    for (int d = 0; d < 16; ++d) he[d] = 0.0f;
    #pragma unroll
    for (int g = 0; g < 8; ++g) {
      float a = sc1[g];
      ushort8v v0 = *(const ushort8v*)&Vh[(size_t)sn1 * DD + g * DKK];
      ushort8v v1 = *(const ushort8v*)&Vh[(size_t)sn1 * DD + g * DKK + 8];
      #pragma unroll
      for (int t = 0; t < 8; ++t) {
        he[t]     = fmaf(a, bf2f(v0[t]), he[t]);
        he[8 + t] = fmaf(a, bf2f(v1[t]), he[8 + t]);
      }
    }
    #pragma unroll
    for (int d0 = 0; d0 < 4; ++d0) {
      float4 t = { he[d0 * 4], he[d0 * 4 + 1], he[d0 * 4 + 2], he[d0 * 4 + 3] };
      *(float4*)&He[i1 * 132 + h * DKK + d0 * 4] = t;
    }
  }
  __syncthreads();

  // ---- parallel chunked flush: 4 chunks x 32 edges, flush on dst change ----
  {
    const int c = tid >> 7, d = tid & 127;
    const int base = c * 32;
    float s = 0.0f;
    int curd = s_dst[base];
    #pragma unroll 8
    for (int j = 0; j < 32; ++j) {
      int i2 = base + j;
      int dn2 = s_dst[i2];
      if (dn2 != curd) {
        atomicAdd(&out[(size_t)curd * DD + d], s);
        s = 0.0f;
        curd = dn2;
      }
      s += He[i2 * 132 + d];
    }
    atomicAdd(&out[(size_t)curd * DD + d], s);
  }
}

// ---------------------------------------------------------------------------
extern "C" void kernel_launch(void* const* d_in, const int* in_sizes, int n_in,
                              void* d_out, int out_size, void* d_ws, size_t ws_size,
                              hipStream_t stream) {
  const float* q  = (const float*)d_in[0];
  const float* k  = (const float*)d_in[1];
  const float* v  = (const float*)d_in[2];
  const float* e  = (const float*)d_in[3];
  const int*   src = (const int*)d_in[4];
  const int*   dst = (const int*)d_in[5];
  const float* Wq = (const float*)d_in[6];
  const float* Wk = (const float*)d_in[7];
  const float* Wv = (const float*)d_in[8];

  float* out = (float*)d_out;
  char* wsb = (char*)d_ws;
  unsigned short* Qh  = (unsigned short*)wsb;                      // 12.8 MB
  unsigned short* Vh  = Qh + (size_t)NN * DD;                      // 12.8 MB
  unsigned short* kh  = Vh + (size_t)NN * DD;                      // 12.8 MB
  unsigned short* WqT = kh + (size_t)NN * DD;                      // 32 KB each
  unsigned short* WkT = WqT + DD * DD;
  unsigned short* WvT = WkT + DD * DD;
  int* cnt    = (int*)(WvT + DD * DD);                             // [NN]
  int* cur    = cnt + NN;                                          // [NN]
  int* rowptr = cur + NN;                                          // [NN+1]
  int* bsum   = rowptr + NN + 1;                                   // [64]
  int* bpre   = bsum + 64;                                         // [64]
  int* perm   = bpre + 64;                                         // [EE]

  hipMemsetAsync(d_out, 0, (size_t)NN * DD * sizeof(float), stream);
  hipMemsetAsync(cnt, 0, 2 * NN * sizeof(int), stream);            // cnt + cur

  hist_kernel <<<(EE / 4 + 255) / 256, 256, 0, stream>>>(dst, cnt);
  scan1_kernel<<<SCAN_NB, 256, 0, stream>>>(cnt, bsum);
  scan2_kernel<<<1, 64, 0, stream>>>(bsum, bpre);
  scan3_kernel<<<SCAN_NB, 256, 0, stream>>>(cnt, bpre, rowptr);
  fill_kernel <<<(EE / 4 + 255) / 256, 256, 0, stream>>>(dst, rowptr, cur, perm);

  prep_w_kernel<<<3 * DD, DD, 0, stream>>>(Wq, Wk, Wv, WqT, WkT, WvT);
  conv_k_kernel<<<(NN * DD / 8 + 255) / 256, 256, 0, stream>>>(k, kh);
  node_proj_kernel<<<(NN + 63) / 64, 512, 0, stream>>>(q, v, WqT, WvT, Qh, Vh);
  edge_attn_kernel<<<EE / 128, 512, 0, stream>>>(kh, e, src, dst, perm,
                                                 WkT, Qh, Vh, out);
}

// Round 8
// 395.968 us; speedup vs baseline: 1.9402x; 1.0121x over previous
//
#include <hip/hip_runtime.h>
#include <hip/hip_bf16.h>
#include <math.h>

#define NN 50000
#define EE 800000
#define DD 128
#define HH 8
#define DKK 16

typedef __attribute__((ext_vector_type(8))) short short8;
typedef __attribute__((ext_vector_type(4))) float f32x4;
typedef __attribute__((ext_vector_type(4))) unsigned short ushort4v;
typedef __attribute__((ext_vector_type(8))) unsigned short ushort8v;

static __device__ __forceinline__ unsigned short f2bf(float x) {
  __hip_bfloat16 h = __float2bfloat16(x);   // RNE
  return *reinterpret_cast<unsigned short*>(&h);
}
static __device__ __forceinline__ float bf2f(unsigned short u) {
  return __uint_as_float(((unsigned int)u) << 16);
}

// ---------------------------------------------------------------------------
// Bucket-by-dst prep: histogram -> 3-dispatch coalesced scan -> perm fill.
// ---------------------------------------------------------------------------
__global__ __launch_bounds__(256) void hist_kernel(const int* __restrict__ dst,
                                                   int* __restrict__ cnt) {
  int i4 = blockIdx.x * 256 + threadIdx.x;
  if (i4 < EE / 4) {
    int4 d = *(const int4*)&dst[i4 * 4];
    atomicAdd(&cnt[d.x], 1);
    atomicAdd(&cnt[d.y], 1);
    atomicAdd(&cnt[d.z], 1);
    atomicAdd(&cnt[d.w], 1);
  }
}

#define SCAN_NB ((NN + 1023) / 1024)   // 49 chunks of 1024

__global__ __launch_bounds__(256) void scan1_kernel(const int* __restrict__ cnt,
                                                    int* __restrict__ bsum) {
  __shared__ int red[256];
  const int b = blockIdx.x, t = threadIdx.x;
  const int base = b * 1024 + t * 4;
  int s = 0;
  if (base + 3 < NN) {
    int4 v = *(const int4*)&cnt[base];
    s = v.x + v.y + v.z + v.w;
  } else {
    for (int j = 0; j < 4; ++j) if (base + j < NN) s += cnt[base + j];
  }
  red[t] = s;
  __syncthreads();
  for (int off = 1; off < 256; off <<= 1) {
    int v = (t >= off) ? red[t - off] : 0;
    __syncthreads();
    red[t] += v;
    __syncthreads();
  }
  if (t == 255) bsum[b] = red[255];
}

__global__ __launch_bounds__(64) void scan2_kernel(const int* __restrict__ bsum,
                                                   int* __restrict__ bpre) {
  int t = threadIdx.x;                      // one wave
  int v = (t < SCAN_NB) ? bsum[t] : 0;
  for (int off = 1; off < 64; off <<= 1) {
    int u = __shfl_up(v, off);
    if (t >= off) v += u;
  }
  if (t < SCAN_NB) bpre[t + 1] = v;
  if (t == 0) bpre[0] = 0;
}

__global__ __launch_bounds__(256) void scan3_kernel(const int* __restrict__ cnt,
                                                    const int* __restrict__ bpre,
                                                    int* __restrict__ rowptr) {
  __shared__ int red[256];
  const int b = blockIdx.x, t = threadIdx.x;
  const int base = b * 1024 + t * 4;
  int v0 = 0, v1 = 0, v2 = 0, v3 = 0;
  if (base + 3 < NN) {
    int4 v = *(const int4*)&cnt[base];
    v0 = v.x; v1 = v.y; v2 = v.z; v3 = v.w;
  } else {
    if (base + 0 < NN) v0 = cnt[base + 0];
    if (base + 1 < NN) v1 = cnt[base + 1];
    if (base + 2 < NN) v2 = cnt[base + 2];
    if (base + 3 < NN) v3 = cnt[base + 3];
  }
  red[t] = v0 + v1 + v2 + v3;
  __syncthreads();
  for (int off = 1; off < 256; off <<= 1) {
    int v = (t >= off) ? red[t - off] : 0;
    __syncthreads();
    red[t] += v;
    __syncthreads();
  }
  int r = bpre[b] + ((t == 0) ? 0 : red[t - 1]);   // exclusive within chunk
  if (base + 0 < NN) { rowptr[base + 0] = r; r += v0; }
  if (base + 1 < NN) { rowptr[base + 1] = r; r += v1; }
  if (base + 2 < NN) { rowptr[base + 2] = r; r += v2; }
  if (base + 3 < NN) { rowptr[base + 3] = r; }
}

__global__ __launch_bounds__(256) void fill_kernel(const int* __restrict__ dst,
                                                   const int* __restrict__ rowptr,
                                                   int* __restrict__ cur,
                                                   int* __restrict__ perm) {
  int i4 = blockIdx.x * 256 + threadIdx.x;
  if (i4 < EE / 4) {
    int4 dv = *(const int4*)&dst[i4 * 4];
    int d0 = dv.x, d1 = dv.y, d2 = dv.z, d3 = dv.w;
    int s0 = atomicAdd(&cur[d0], 1); perm[rowptr[d0] + s0] = i4 * 4 + 0;
    int s1 = atomicAdd(&cur[d1], 1); perm[rowptr[d1] + s1] = i4 * 4 + 1;
    int s2 = atomicAdd(&cur[d2], 1); perm[rowptr[d2] + s2] = i4 * 4 + 2;
    int s3 = atomicAdd(&cur[d3], 1); perm[rowptr[d3] + s3] = i4 * 4 + 3;
  }
}

// ---------------------------------------------------------------------------
// Prep: WT[j][c] = bf16(W[c][j])
// ---------------------------------------------------------------------------
__global__ void prep_w_kernel(const float* __restrict__ Wq,
                              const float* __restrict__ Wk,
                              const float* __restrict__ Wv,
                              unsigned short* __restrict__ WqT,
                              unsigned short* __restrict__ WkT,
                              unsigned short* __restrict__ WvT) {
  int c = blockIdx.x & 127;
  int m = blockIdx.x >> 7;
  int j = threadIdx.x;
  const float* W = (m == 0) ? Wq : (m == 1) ? Wk : Wv;
  unsigned short* o = (m == 0) ? WqT : (m == 1) ? WkT : WvT;
  o[j * DD + c] = f2bf(W[c * DD + j]);
}

// ---------------------------------------------------------------------------
// Kernel 1: node projections via MFMA + fused k->bf16 conversion.
// ---------------------------------------------------------------------------
__global__ __launch_bounds__(512) void node_proj_kernel(
    const float* __restrict__ q, const float* __restrict__ v,
    const float* __restrict__ k,
    const unsigned short* __restrict__ WqT, const unsigned short* __restrict__ WvT,
    unsigned short* __restrict__ Qh, unsigned short* __restrict__ Vh,
    unsigned short* __restrict__ kh)
{
  __shared__ __align__(16) unsigned short xl[64 * 136];
  const int tid = threadIdx.x;
  const int n0 = blockIdx.x * 64;

  // ---- fused: convert this block's 64 k-rows to bf16 (no sync needed) ----
  #pragma unroll
  for (int p = 0; p < 2; ++p) {
    int f = p * 512 + tid;              // 1024 chunks of 8
    int i = f >> 4, c8 = f & 15;
    int n = n0 + i;
    if (n < NN) {
      float4 a = *(const float4*)&k[(size_t)n * DD + c8 * 8];
      float4 b = *(const float4*)&k[(size_t)n * DD + c8 * 8 + 4];
      ushort8v o = { f2bf(a.x), f2bf(a.y), f2bf(a.z), f2bf(a.w),
                     f2bf(b.x), f2bf(b.y), f2bf(b.z), f2bf(b.w) };
      *(ushort8v*)&kh[(size_t)n * DD + c8 * 8] = o;
    }
  }

  for (int m = 0; m < 2; ++m) {
    const float* x = m ? v : q;
    const unsigned short* WT = m ? WvT : WqT;
    unsigned short* o = m ? Vh : Qh;

    __syncthreads();
    #pragma unroll
    for (int p = 0; p < 4; ++p) {
      int f = p * 512 + tid;
      int i = f >> 5, c4 = f & 31;
      int n = n0 + i;
      float4 t = (n < NN) ? *(const float4*)&x[(size_t)n * DD + c4 * 4]
                          : float4{0.f, 0.f, 0.f, 0.f};
      ushort4v u = { f2bf(t.x), f2bf(t.y), f2bf(t.z), f2bf(t.w) };
      *(ushort4v*)&xl[i * 136 + c4 * 4] = u;
    }
    __syncthreads();

    const int lane = tid & 63, wid = tid >> 6;
    const int rg = wid & 3, cg = wid >> 2;
    const int lr = lane & 15, lg = lane >> 4;

    f32x4 acc0 = {0.f,0.f,0.f,0.f}, acc1 = {0.f,0.f,0.f,0.f};
    f32x4 acc2 = {0.f,0.f,0.f,0.f}, acc3 = {0.f,0.f,0.f,0.f};

    const unsigned short* Ab = &xl[(rg * 16 + lr) * 136];
    const unsigned short* B0 = &WT[(size_t)(cg * 64 +  0 + lr) * DD];
    const unsigned short* B1 = &WT[(size_t)(cg * 64 + 16 + lr) * DD];
    const unsigned short* B2 = &WT[(size_t)(cg * 64 + 32 + lr) * DD];
    const unsigned short* B3 = &WT[(size_t)(cg * 64 + 48 + lr) * DD];

    #pragma unroll
    for (int kk = 0; kk < 4; ++kk) {
      const int kof = kk * 32 + lg * 8;
      short8 a = *(const short8*)(Ab + kof);
      acc0 = __builtin_amdgcn_mfma_f32_16x16x32_bf16(a, *(const short8*)(B0 + kof), acc0, 0, 0, 0);
      acc1 = __builtin_amdgcn_mfma_f32_16x16x32_bf16(a, *(const short8*)(B1 + kof), acc1, 0, 0, 0);
      acc2 = __builtin_amdgcn_mfma_f32_16x16x32_bf16(a, *(const short8*)(B2 + kof), acc2, 0, 0, 0);
      acc3 = __builtin_amdgcn_mfma_f32_16x16x32_bf16(a, *(const short8*)(B3 + kof), acc3, 0, 0, 0);
    }

    const int r0 = rg * 16 + lg * 4;
    const int cb = cg * 64 + lr;
    #pragma unroll
    for (int r = 0; r < 4; ++r) {
      int n = n0 + r0 + r;
      if (n < NN) {
        unsigned short* orow = &o[(size_t)n * DD + cb];
        orow[ 0] = f2bf(acc0[r]);
        orow[16] = f2bf(acc1[r]);
        orow[32] = f2bf(acc2[r]);
        orow[48] = f2bf(acc3[r]);
      }
    }
  }
}

// ---------------------------------------------------------------------------
// Kernel 2: fused edge attention, 128 dst-sorted edges/block, 512 threads.
// SINGLE LDS buffer [128][136] bf16 (36.4KB total): kke -> Ke (in-place,
// guarded by a barrier between MFMA reads and writeback) -> He (bf16).
// 4 blocks/CU -> 32 waves (was 2 blocks / 16 waves).
// ---------------------------------------------------------------------------
__global__ __launch_bounds__(512) void edge_attn_kernel(
    const unsigned short* __restrict__ kh, const float* __restrict__ e,
    const int* __restrict__ src, const int* __restrict__ dst,
    const int* __restrict__ perm,
    const unsigned short* __restrict__ WkT,
    const unsigned short* __restrict__ Qh, const unsigned short* __restrict__ Vh,
    float* __restrict__ out)
{
  __shared__ __align__(16) unsigned short buf[128 * 136];   // 34816 B
  __shared__ int s_perm[128], s_src[128], s_dst[128];

  const int tid = threadIdx.x;
  const size_t e0 = (size_t)blockIdx.x * 128;

  if (tid < 128) {
    int pe = perm[e0 + tid];
    s_perm[tid] = pe;
    s_src[tid] = src[pe];
    s_dst[tid] = dst[pe];
  }
  __syncthreads();

  // ---- early-issue Q gather for this thread's two (edge, head) slots ----
  const int i0 = tid >> 3, i1 = i0 + 64, h = tid & 7;
  const int sn0 = s_src[i0], dn0 = s_dst[i0];
  const int sn1 = s_src[i1], dn1 = s_dst[i1];
  ushort8v qa0 = *(const ushort8v*)&Qh[(size_t)dn0 * DD + h * DKK];
  ushort8v qa1 = *(const ushort8v*)&Qh[(size_t)dn0 * DD + h * DKK + 8];
  ushort8v qb0 = *(const ushort8v*)&Qh[(size_t)dn1 * DD + h * DKK];
  ushort8v qb1 = *(const ushort8v*)&Qh[(size_t)dn1 * DD + h * DKK + 8];

  // ---- stage kke[i][c] = bf16(kh[src_i][c] + e[perm_i][c]) ----
  #pragma unroll
  for (int p = 0; p < 4; ++p) {
    int f = p * 512 + tid;              // 2048 chunks of 8 cols
    int i2 = f >> 4, c8 = f & 15;
    ushort8v kv = *(const ushort8v*)&kh[(size_t)s_src[i2] * DD + c8 * 8];
    float4 ea = *(const float4*)&e[(size_t)s_perm[i2] * DD + c8 * 8];
    float4 eb = *(const float4*)&e[(size_t)s_perm[i2] * DD + c8 * 8 + 4];
    ushort8v o;
    o[0] = f2bf(bf2f(kv[0]) + ea.x);
    o[1] = f2bf(bf2f(kv[1]) + ea.y);
    o[2] = f2bf(bf2f(kv[2]) + ea.z);
    o[3] = f2bf(bf2f(kv[3]) + ea.w);
    o[4] = f2bf(bf2f(kv[4]) + eb.x);
    o[5] = f2bf(bf2f(kv[5]) + eb.y);
    o[6] = f2bf(bf2f(kv[6]) + eb.z);
    o[7] = f2bf(bf2f(kv[7]) + eb.w);
    *(ushort8v*)&buf[i2 * 136 + c8 * 8] = o;
  }
  __syncthreads();

  // ---- phase 1: Ke = kke @ Wk, written back IN PLACE over kke ----
  {
    const int lane = tid & 63, wid = tid >> 6;
    const int rgA = wid & 3, rgB = (wid & 3) + 4, cg = wid >> 2;
    const int lr = lane & 15, lg = lane >> 4;

    f32x4 aA0 = {0.f,0.f,0.f,0.f}, aA1 = {0.f,0.f,0.f,0.f};
    f32x4 aA2 = {0.f,0.f,0.f,0.f}, aA3 = {0.f,0.f,0.f,0.f};
    f32x4 aB0 = {0.f,0.f,0.f,0.f}, aB1 = {0.f,0.f,0.f,0.f};
    f32x4 aB2 = {0.f,0.f,0.f,0.f}, aB3 = {0.f,0.f,0.f,0.f};

    const unsigned short* AbA = &buf[(rgA * 16 + lr) * 136];
    const unsigned short* AbB = &buf[(rgB * 16 + lr) * 136];
    const unsigned short* B0 = &WkT[(size_t)(cg * 64 +  0 + lr) * DD];
    const unsigned short* B1 = &WkT[(size_t)(cg * 64 + 16 + lr) * DD];
    const unsigned short* B2 = &WkT[(size_t)(cg * 64 + 32 + lr) * DD];
    const unsigned short* B3 = &WkT[(size_t)(cg * 64 + 48 + lr) * DD];

    #pragma unroll
    for (int kk = 0; kk < 4; ++kk) {
      const int kof = kk * 32 + lg * 8;
      short8 b0 = *(const short8*)(B0 + kof);
      short8 b1 = *(const short8*)(B1 + kof);
      short8 b2 = *(const short8*)(B2 + kof);
      short8 b3 = *(const short8*)(B3 + kof);
      short8 fA = *(const short8*)(AbA + kof);
      short8 fB = *(const short8*)(AbB + kof);
      aA0 = __builtin_amdgcn_mfma_f32_16x16x32_bf16(fA, b0, aA0, 0, 0, 0);
      aA1 = __builtin_amdgcn_mfma_f32_16x16x32_bf16(fA, b1, aA1, 0, 0, 0);
      aA2 = __builtin_amdgcn_mfma_f32_16x16x32_bf16(fA, b2, aA2, 0, 0, 0);
      aA3 = __builtin_amdgcn_mfma_f32_16x16x32_bf16(fA, b3, aA3, 0, 0, 0);
      aB0 = __builtin_amdgcn_mfma_f32_16x16x32_bf16(fB, b0, aB0, 0, 0, 0);
      aB1 = __builtin_amdgcn_mfma_f32_16x16x32_bf16(fB, b1, aB1, 0, 0, 0);
      aB2 = __builtin_amdgcn_mfma_f32_16x16x32_bf16(fB, b2, aB2, 0, 0, 0);
      aB3 = __builtin_amdgcn_mfma_f32_16x16x32_bf16(fB, b3, aB3, 0, 0, 0);
    }

    __syncthreads();   // ALL waves done reading kke before any Ke overwrite

    const int rA = rgA * 16 + lg * 4;
    const int rB = rgB * 16 + lg * 4;
    const int cb = cg * 64 + lr;
    #pragma unroll
    for (int r = 0; r < 4; ++r) {
      buf[(rA + r) * 136 + cb +  0] = f2bf(aA0[r]);
      buf[(rA + r) * 136 + cb + 16] = f2bf(aA1[r]);
      buf[(rA + r) * 136 + cb + 32] = f2bf(aA2[r]);
      buf[(rA + r) * 136 + cb + 48] = f2bf(aA3[r]);
      buf[(rB + r) * 136 + cb +  0] = f2bf(aB0[r]);
      buf[(rB + r) * 136 + cb + 16] = f2bf(aB1[r]);
      buf[(rB + r) * 136 + cb + 32] = f2bf(aB2[r]);
      buf[(rB + r) * 136 + cb + 48] = f2bf(aB3[r]);
    }
  }
  __syncthreads();   // Ke ready

  // ---- phase 2a: scores + softmax for both edges (reads Ke + Q regs) ----
  float sc0[8], sc1[8];
  {
    #pragma unroll
    for (int g = 0; g < 8; ++g) {
      const ushort8v* kp = (const ushort8v*)&buf[i0 * 136 + g * DKK];
      ushort8v k0 = kp[0], k1 = kp[1];
      float a = 0.0f;
      #pragma unroll
      for (int t = 0; t < 8; ++t) a = fmaf(bf2f(qa0[t]), bf2f(k0[t]), a);
      #pragma unroll
      for (int t = 0; t < 8; ++t) a = fmaf(bf2f(qa1[t]), bf2f(k1[t]), a);
      a *= 0.25f;
      sc0[g] = (a >= 0.0f) ? a : 0.01f * a;
    }
    #pragma unroll
    for (int g = 0; g < 8; ++g) {
      const ushort8v* kp = (const ushort8v*)&buf[i1 * 136 + g * DKK];
      ushort8v k0 = kp[0], k1 = kp[1];
      float a = 0.0f;
      #pragma unroll
      for (int t = 0; t < 8; ++t) a = fmaf(bf2f(qb0[t]), bf2f(k0[t]), a);
      #pragma unroll
      for (int t = 0; t < 8; ++t) a = fmaf(bf2f(qb1[t]), bf2f(k1[t]), a);
      a *= 0.25f;
      sc1[g] = (a >= 0.0f) ? a : 0.01f * a;
    }
    float mx0 = sc0[0], mx1 = sc1[0];
    #pragma unroll
    for (int g = 1; g < 8; ++g) { mx0 = fmaxf(mx0, sc0[g]); mx1 = fmaxf(mx1, sc1[g]); }
    float su0 = 0.0f, su1 = 0.0f;
    #pragma unroll
    for (int g = 0; g < 8; ++g) {
      sc0[g] = __expf(sc0[g] - mx0); su0 += sc0[g];
      sc1[g] = __expf(sc1[g] - mx1); su1 += sc1[g];
    }
    float r0 = 1.0f / su0, r1 = 1.0f / su1;
    #pragma unroll
    for (int g = 0; g < 8; ++g) { sc0[g] *= r0; sc1[g] *= r1; }
  }
  __syncthreads();   // all Ke reads done -> He may overwrite buf

  // ---- phase 2b: He = A @ Ve (bf16 V gather), stored bf16 in buf ----
  {
    float he[16];
    #pragma unroll
    for (int d = 0; d < 16; ++d) he[d] = 0.0f;
    #pragma unroll
    for (int g = 0; g < 8; ++g) {
      float a = sc0[g];
      ushort8v v0 = *(const ushort8v*)&Vh[(size_t)sn0 * DD + g * DKK];
      ushort8v v1 = *(const ushort8v*)&Vh[(size_t)sn0 * DD + g * DKK + 8];
      #pragma unroll
      for (int t = 0; t < 8; ++t) {
        he[t]     = fmaf(a, bf2f(v0[t]), he[t]);
        he[8 + t] = fmaf(a, bf2f(v1[t]), he[8 + t]);
      }
    }
    ushort8v o0, o1;
    #pragma unroll
    for (int t = 0; t < 8; ++t) { o0[t] = f2bf(he[t]); o1[t] = f2bf(he[8 + t]); }
    *(ushort8v*)&buf[i0 * 136 + h * DKK]     = o0;
    *(ushort8v*)&buf[i0 * 136 + h * DKK + 8] = o1;

    #pragma unroll
    for (int d = 0; d < 16; ++d) he[d] = 0.0f;
    #pragma unroll
    for (int g = 0; g < 8; ++g) {
      float a = sc1[g];
      ushort8v v0 = *(const ushort8v*)&Vh[(size_t)sn1 * DD + g * DKK];
      ushort8v v1 = *(const ushort8v*)&Vh[(size_t)sn1 * DD + g * DKK + 8];
      #pragma unroll
      for (int t = 0; t < 8; ++t) {
        he[t]     = fmaf(a, bf2f(v0[t]), he[t]);
        he[8 + t] = fmaf(a, bf2f(v1[t]), he[8 + t]);
      }
    }
    #pragma unroll
    for (int t = 0; t < 8; ++t) { o0[t] = f2bf(he[t]); o1[t] = f2bf(he[8 + t]); }
    *(ushort8v*)&buf[i1 * 136 + h * DKK]     = o0;
    *(ushort8v*)&buf[i1 * 136 + h * DKK + 8] = o1;
  }
  __syncthreads();

  // ---- parallel chunked flush: 4 chunks x 32 edges, flush on dst change ----
  {
    const int c = tid >> 7, d = tid & 127;
    const int base = c * 32;
    float s = 0.0f;
    int curd = s_dst[base];
    #pragma unroll 8
    for (int j = 0; j < 32; ++j) {
      int i2 = base + j;
      int dn2 = s_dst[i2];
      if (dn2 != curd) {
        atomicAdd(&out[(size_t)curd * DD + d], s);
        s = 0.0f;
        curd = dn2;
      }
      s += bf2f(buf[i2 * 136 + d]);
    }
    atomicAdd(&out[(size_t)curd * DD + d], s);
  }
}

// ---------------------------------------------------------------------------
extern "C" void kernel_launch(void* const* d_in, const int* in_sizes, int n_in,
                              void* d_out, int out_size, void* d_ws, size_t ws_size,
                              hipStream_t stream) {
  const float* q  = (const float*)d_in[0];
  const float* k  = (const float*)d_in[1];
  const float* v  = (const float*)d_in[2];
  const float* e  = (const float*)d_in[3];
  const int*   src = (const int*)d_in[4];
  const int*   dst = (const int*)d_in[5];
  const float* Wq = (const float*)d_in[6];
  const float* Wk = (const float*)d_in[7];
  const float* Wv = (const float*)d_in[8];

  float* out = (float*)d_out;
  char* wsb = (char*)d_ws;
  unsigned short* Qh  = (unsigned short*)wsb;                      // 12.8 MB
  unsigned short* Vh  = Qh + (size_t)NN * DD;                      // 12.8 MB
  unsigned short* kh  = Vh + (size_t)NN * DD;                      // 12.8 MB
  unsigned short* WqT = kh + (size_t)NN * DD;                      // 32 KB each
  unsigned short* WkT = WqT + DD * DD;
  unsigned short* WvT = WkT + DD * DD;
  int* cnt    = (int*)(WvT + DD * DD);                             // [NN]
  int* cur    = cnt + NN;                                          // [NN]
  int* rowptr = cur + NN;                                          // [NN+1]
  int* bsum   = rowptr + NN + 1;                                   // [64]
  int* bpre   = bsum + 64;                                         // [64]
  int* perm   = bpre + 64;                                         // [EE]

  hipMemsetAsync(d_out, 0, (size_t)NN * DD * sizeof(float), stream);
  hipMemsetAsync(cnt, 0, 2 * NN * sizeof(int), stream);            // cnt + cur

  hist_kernel <<<(EE / 4 + 255) / 256, 256, 0, stream>>>(dst, cnt);
  scan1_kernel<<<SCAN_NB, 256, 0, stream>>>(cnt, bsum);
  scan2_kernel<<<1, 64, 0, stream>>>(bsum, bpre);
  scan3_kernel<<<SCAN_NB, 256, 0, stream>>>(cnt, bpre, rowptr);
  fill_kernel <<<(EE / 4 + 255) / 256, 256, 0, stream>>>(dst, rowptr, cur, perm);

  prep_w_kernel<<<3 * DD, DD, 0, stream>>>(Wq, Wk, Wv, WqT, WkT, WvT);
  node_proj_kernel<<<(NN + 63) / 64, 512, 0, stream>>>(q, v, k, WqT, WvT,
                                                       Qh, Vh, kh);
  edge_attn_kernel<<<EE / 128, 512, 0, stream>>>(kh, e, src, dst, perm,
                                                 WkT, Qh, Vh, out);
}

// Round 9
// 378.523 us; speedup vs baseline: 2.0296x; 1.0461x over previous
//
#include <hip/hip_runtime.h>
#include <hip/hip_bf16.h>
#include <math.h>

#define NN 50000
#define EE 800000
#define DD 128
#define HH 8
#define DKK 16

typedef __attribute__((ext_vector_type(8))) short short8;
typedef __attribute__((ext_vector_type(4))) float f32x4;
typedef __attribute__((ext_vector_type(4))) unsigned short ushort4v;
typedef __attribute__((ext_vector_type(8))) unsigned short ushort8v;

static __device__ __forceinline__ unsigned short f2bf(float x) {
  __hip_bfloat16 h = __float2bfloat16(x);   // RNE
  return *reinterpret_cast<unsigned short*>(&h);
}
static __device__ __forceinline__ float bf2f(unsigned short u) {
  return __uint_as_float(((unsigned int)u) << 16);
}

// ---------------------------------------------------------------------------
// Bucket-by-dst prep: histogram -> 3-dispatch coalesced scan -> perm fill.
// ---------------------------------------------------------------------------
__global__ __launch_bounds__(256) void hist_kernel(const int* __restrict__ dst,
                                                   int* __restrict__ cnt) {
  int i4 = blockIdx.x * 256 + threadIdx.x;
  if (i4 < EE / 4) {
    int4 d = *(const int4*)&dst[i4 * 4];
    atomicAdd(&cnt[d.x], 1);
    atomicAdd(&cnt[d.y], 1);
    atomicAdd(&cnt[d.z], 1);
    atomicAdd(&cnt[d.w], 1);
  }
}

#define SCAN_NB ((NN + 1023) / 1024)   // 49 chunks of 1024

__global__ __launch_bounds__(256) void scan1_kernel(const int* __restrict__ cnt,
                                                    int* __restrict__ bsum) {
  __shared__ int red[256];
  const int b = blockIdx.x, t = threadIdx.x;
  const int base = b * 1024 + t * 4;
  int s = 0;
  if (base + 3 < NN) {
    int4 v = *(const int4*)&cnt[base];
    s = v.x + v.y + v.z + v.w;
  } else {
    for (int j = 0; j < 4; ++j) if (base + j < NN) s += cnt[base + j];
  }
  red[t] = s;
  __syncthreads();
  for (int off = 1; off < 256; off <<= 1) {
    int v = (t >= off) ? red[t - off] : 0;
    __syncthreads();
    red[t] += v;
    __syncthreads();
  }
  if (t == 255) bsum[b] = red[255];
}

__global__ __launch_bounds__(64) void scan2_kernel(const int* __restrict__ bsum,
                                                   int* __restrict__ bpre) {
  int t = threadIdx.x;                      // one wave
  int v = (t < SCAN_NB) ? bsum[t] : 0;
  for (int off = 1; off < 64; off <<= 1) {
    int u = __shfl_up(v, off);
    if (t >= off) v += u;
  }
  if (t < SCAN_NB) bpre[t + 1] = v;
  if (t == 0) bpre[0] = 0;
}

__global__ __launch_bounds__(256) void scan3_kernel(const int* __restrict__ cnt,
                                                    const int* __restrict__ bpre,
                                                    int* __restrict__ rowptr) {
  __shared__ int red[256];
  const int b = blockIdx.x, t = threadIdx.x;
  const int base = b * 1024 + t * 4;
  int v0 = 0, v1 = 0, v2 = 0, v3 = 0;
  if (base + 3 < NN) {
    int4 v = *(const int4*)&cnt[base];
    v0 = v.x; v1 = v.y; v2 = v.z; v3 = v.w;
  } else {
    if (base + 0 < NN) v0 = cnt[base + 0];
    if (base + 1 < NN) v1 = cnt[base + 1];
    if (base + 2 < NN) v2 = cnt[base + 2];
    if (base + 3 < NN) v3 = cnt[base + 3];
  }
  red[t] = v0 + v1 + v2 + v3;
  __syncthreads();
  for (int off = 1; off < 256; off <<= 1) {
    int v = (t >= off) ? red[t - off] : 0;
    __syncthreads();
    red[t] += v;
    __syncthreads();
  }
  int r = bpre[b] + ((t == 0) ? 0 : red[t - 1]);   // exclusive within chunk
  if (base + 0 < NN) { rowptr[base + 0] = r; r += v0; }
  if (base + 1 < NN) { rowptr[base + 1] = r; r += v1; }
  if (base + 2 < NN) { rowptr[base + 2] = r; r += v2; }
  if (base + 3 < NN) { rowptr[base + 3] = r; }
}

__global__ __launch_bounds__(256) void fill_kernel(const int* __restrict__ dst,
                                                   const int* __restrict__ rowptr,
                                                   int* __restrict__ cur,
                                                   int* __restrict__ perm) {
  int i4 = blockIdx.x * 256 + threadIdx.x;
  if (i4 < EE / 4) {
    int4 dv = *(const int4*)&dst[i4 * 4];
    int d0 = dv.x, d1 = dv.y, d2 = dv.z, d3 = dv.w;
    int s0 = atomicAdd(&cur[d0], 1); perm[rowptr[d0] + s0] = i4 * 4 + 0;
    int s1 = atomicAdd(&cur[d1], 1); perm[rowptr[d1] + s1] = i4 * 4 + 1;
    int s2 = atomicAdd(&cur[d2], 1); perm[rowptr[d2] + s2] = i4 * 4 + 2;
    int s3 = atomicAdd(&cur[d3], 1); perm[rowptr[d3] + s3] = i4 * 4 + 3;
  }
}

// ---------------------------------------------------------------------------
// Prep: WT[j][c] = bf16(W[c][j])
// ---------------------------------------------------------------------------
__global__ void prep_w_kernel(const float* __restrict__ Wq,
                              const float* __restrict__ Wk,
                              const float* __restrict__ Wv,
                              unsigned short* __restrict__ WqT,
                              unsigned short* __restrict__ WkT,
                              unsigned short* __restrict__ WvT) {
  int c = blockIdx.x & 127;
  int m = blockIdx.x >> 7;
  int j = threadIdx.x;
  const float* W = (m == 0) ? Wq : (m == 1) ? Wk : Wv;
  unsigned short* o = (m == 0) ? WqT : (m == 1) ? WkT : WvT;
  o[j * DD + c] = f2bf(W[c * DD + j]);
}

// ---------------------------------------------------------------------------
// Kernel 1: node projections via MFMA + fused k->bf16 conversion.
// ---------------------------------------------------------------------------
__global__ __launch_bounds__(512) void node_proj_kernel(
    const float* __restrict__ q, const float* __restrict__ v,
    const float* __restrict__ k,
    const unsigned short* __restrict__ WqT, const unsigned short* __restrict__ WvT,
    unsigned short* __restrict__ Qh, unsigned short* __restrict__ Vh,
    unsigned short* __restrict__ kh)
{
  __shared__ __align__(16) unsigned short xl[64 * 136];
  const int tid = threadIdx.x;
  const int n0 = blockIdx.x * 64;

  // ---- fused: convert this block's 64 k-rows to bf16 (no sync needed) ----
  #pragma unroll
  for (int p = 0; p < 2; ++p) {
    int f = p * 512 + tid;              // 1024 chunks of 8
    int i = f >> 4, c8 = f & 15;
    int n = n0 + i;
    if (n < NN) {
      float4 a = *(const float4*)&k[(size_t)n * DD + c8 * 8];
      float4 b = *(const float4*)&k[(size_t)n * DD + c8 * 8 + 4];
      ushort8v o = { f2bf(a.x), f2bf(a.y), f2bf(a.z), f2bf(a.w),
                     f2bf(b.x), f2bf(b.y), f2bf(b.z), f2bf(b.w) };
      *(ushort8v*)&kh[(size_t)n * DD + c8 * 8] = o;
    }
  }

  for (int m = 0; m < 2; ++m) {
    const float* x = m ? v : q;
    const unsigned short* WT = m ? WvT : WqT;
    unsigned short* o = m ? Vh : Qh;

    __syncthreads();
    #pragma unroll
    for (int p = 0; p < 4; ++p) {
      int f = p * 512 + tid;
      int i = f >> 5, c4 = f & 31;
      int n = n0 + i;
      float4 t = (n < NN) ? *(const float4*)&x[(size_t)n * DD + c4 * 4]
                          : float4{0.f, 0.f, 0.f, 0.f};
      ushort4v u = { f2bf(t.x), f2bf(t.y), f2bf(t.z), f2bf(t.w) };
      *(ushort4v*)&xl[i * 136 + c4 * 4] = u;
    }
    __syncthreads();

    const int lane = tid & 63, wid = tid >> 6;
    const int rg = wid & 3, cg = wid >> 2;
    const int lr = lane & 15, lg = lane >> 4;

    f32x4 acc0 = {0.f,0.f,0.f,0.f}, acc1 = {0.f,0.f,0.f,0.f};
    f32x4 acc2 = {0.f,0.f,0.f,0.f}, acc3 = {0.f,0.f,0.f,0.f};

    const unsigned short* Ab = &xl[(rg * 16 + lr) * 136];
    const unsigned short* B0 = &WT[(size_t)(cg * 64 +  0 + lr) * DD];
    const unsigned short* B1 = &WT[(size_t)(cg * 64 + 16 + lr) * DD];
    const unsigned short* B2 = &WT[(size_t)(cg * 64 + 32 + lr) * DD];
    const unsigned short* B3 = &WT[(size_t)(cg * 64 + 48 + lr) * DD];

    #pragma unroll
    for (int kk = 0; kk < 4; ++kk) {
      const int kof = kk * 32 + lg * 8;
      short8 a = *(const short8*)(Ab + kof);
      acc0 = __builtin_amdgcn_mfma_f32_16x16x32_bf16(a, *(const short8*)(B0 + kof), acc0, 0, 0, 0);
      acc1 = __builtin_amdgcn_mfma_f32_16x16x32_bf16(a, *(const short8*)(B1 + kof), acc1, 0, 0, 0);
      acc2 = __builtin_amdgcn_mfma_f32_16x16x32_bf16(a, *(const short8*)(B2 + kof), acc2, 0, 0, 0);
      acc3 = __builtin_amdgcn_mfma_f32_16x16x32_bf16(a, *(const short8*)(B3 + kof), acc3, 0, 0, 0);
    }

    const int r0 = rg * 16 + lg * 4;
    const int cb = cg * 64 + lr;
    #pragma unroll
    for (int r = 0; r < 4; ++r) {
      int n = n0 + r0 + r;
      if (n < NN) {
        unsigned short* orow = &o[(size_t)n * DD + cb];
        orow[ 0] = f2bf(acc0[r]);
        orow[16] = f2bf(acc1[r]);
        orow[32] = f2bf(acc2[r]);
        orow[48] = f2bf(acc3[r]);
      }
    }
  }
}

// ---------------------------------------------------------------------------
// Kernel 2: fused edge attention, 128 dst-sorted edges/block, 512 threads.
// buf: kke -> Ke (in-place) -> He (bf16).  vbuf: Ve staged cooperatively
// (kills the 8x redundant per-head V global loads; loads issued at the TOP so
// HBM latency hides under kke staging + MFMA).  LDS ~71KB, 2 blocks/CU
// (occupancy is register-capped at 16 waves/CU anyway — r8 finding).
// ---------------------------------------------------------------------------
__global__ __launch_bounds__(512) void edge_attn_kernel(
    const unsigned short* __restrict__ kh, const float* __restrict__ e,
    const int* __restrict__ src, const int* __restrict__ dst,
    const int* __restrict__ perm,
    const unsigned short* __restrict__ WkT,
    const unsigned short* __restrict__ Qh, const unsigned short* __restrict__ Vh,
    float* __restrict__ out)
{
  __shared__ __align__(16) unsigned short buf[128 * 136];    // 34816 B
  __shared__ __align__(16) unsigned short vbuf[128 * 136];   // 34816 B
  __shared__ int s_perm[128], s_src[128], s_dst[128];

  const int tid = threadIdx.x;
  const size_t e0 = (size_t)blockIdx.x * 128;

  if (tid < 128) {
    int pe = perm[e0 + tid];
    s_perm[tid] = pe;
    s_src[tid] = src[pe];
    s_dst[tid] = dst[pe];
  }
  __syncthreads();

  // ---- EARLY: stage Ve rows into LDS (coalesced ushort8 copy, no conv) ----
  #pragma unroll
  for (int p = 0; p < 4; ++p) {
    int f = p * 512 + tid;              // 2048 chunks of 8 cols
    int i2 = f >> 4, c8 = f & 15;
    *(ushort8v*)&vbuf[i2 * 136 + c8 * 8] =
        *(const ushort8v*)&Vh[(size_t)s_src[i2] * DD + c8 * 8];
  }

  // ---- early-issue Q gather for this thread's two (edge, head) slots ----
  const int i0 = tid >> 3, i1 = i0 + 64, h = tid & 7;
  const int dn0 = s_dst[i0], dn1 = s_dst[i1];
  ushort8v qa0 = *(const ushort8v*)&Qh[(size_t)dn0 * DD + h * DKK];
  ushort8v qa1 = *(const ushort8v*)&Qh[(size_t)dn0 * DD + h * DKK + 8];
  ushort8v qb0 = *(const ushort8v*)&Qh[(size_t)dn1 * DD + h * DKK];
  ushort8v qb1 = *(const ushort8v*)&Qh[(size_t)dn1 * DD + h * DKK + 8];

  // ---- stage kke[i][c] = bf16(kh[src_i][c] + e[perm_i][c]) ----
  #pragma unroll
  for (int p = 0; p < 4; ++p) {
    int f = p * 512 + tid;              // 2048 chunks of 8 cols
    int i2 = f >> 4, c8 = f & 15;
    ushort8v kv = *(const ushort8v*)&kh[(size_t)s_src[i2] * DD + c8 * 8];
    float4 ea = *(const float4*)&e[(size_t)s_perm[i2] * DD + c8 * 8];
    float4 eb = *(const float4*)&e[(size_t)s_perm[i2] * DD + c8 * 8 + 4];
    ushort8v o;
    o[0] = f2bf(bf2f(kv[0]) + ea.x);
    o[1] = f2bf(bf2f(kv[1]) + ea.y);
    o[2] = f2bf(bf2f(kv[2]) + ea.z);
    o[3] = f2bf(bf2f(kv[3]) + ea.w);
    o[4] = f2bf(bf2f(kv[4]) + eb.x);
    o[5] = f2bf(bf2f(kv[5]) + eb.y);
    o[6] = f2bf(bf2f(kv[6]) + eb.z);
    o[7] = f2bf(bf2f(kv[7]) + eb.w);
    *(ushort8v*)&buf[i2 * 136 + c8 * 8] = o;
  }
  __syncthreads();

  // ---- phase 1: Ke = kke @ Wk, written back IN PLACE over kke ----
  {
    const int lane = tid & 63, wid = tid >> 6;
    const int rgA = wid & 3, rgB = (wid & 3) + 4, cg = wid >> 2;
    const int lr = lane & 15, lg = lane >> 4;

    f32x4 aA0 = {0.f,0.f,0.f,0.f}, aA1 = {0.f,0.f,0.f,0.f};
    f32x4 aA2 = {0.f,0.f,0.f,0.f}, aA3 = {0.f,0.f,0.f,0.f};
    f32x4 aB0 = {0.f,0.f,0.f,0.f}, aB1 = {0.f,0.f,0.f,0.f};
    f32x4 aB2 = {0.f,0.f,0.f,0.f}, aB3 = {0.f,0.f,0.f,0.f};

    const unsigned short* AbA = &buf[(rgA * 16 + lr) * 136];
    const unsigned short* AbB = &buf[(rgB * 16 + lr) * 136];
    const unsigned short* B0 = &WkT[(size_t)(cg * 64 +  0 + lr) * DD];
    const unsigned short* B1 = &WkT[(size_t)(cg * 64 + 16 + lr) * DD];
    const unsigned short* B2 = &WkT[(size_t)(cg * 64 + 32 + lr) * DD];
    const unsigned short* B3 = &WkT[(size_t)(cg * 64 + 48 + lr) * DD];

    #pragma unroll
    for (int kk = 0; kk < 4; ++kk) {
      const int kof = kk * 32 + lg * 8;
      short8 b0 = *(const short8*)(B0 + kof);
      short8 b1 = *(const short8*)(B1 + kof);
      short8 b2 = *(const short8*)(B2 + kof);
      short8 b3 = *(const short8*)(B3 + kof);
      short8 fA = *(const short8*)(AbA + kof);
      short8 fB = *(const short8*)(AbB + kof);
      aA0 = __builtin_amdgcn_mfma_f32_16x16x32_bf16(fA, b0, aA0, 0, 0, 0);
      aA1 = __builtin_amdgcn_mfma_f32_16x16x32_bf16(fA, b1, aA1, 0, 0, 0);
      aA2 = __builtin_amdgcn_mfma_f32_16x16x32_bf16(fA, b2, aA2, 0, 0, 0);
      aA3 = __builtin_amdgcn_mfma_f32_16x16x32_bf16(fA, b3, aA3, 0, 0, 0);
      aB0 = __builtin_amdgcn_mfma_f32_16x16x32_bf16(fB, b0, aB0, 0, 0, 0);
      aB1 = __builtin_amdgcn_mfma_f32_16x16x32_bf16(fB, b1, aB1, 0, 0, 0);
      aB2 = __builtin_amdgcn_mfma_f32_16x16x32_bf16(fB, b2, aB2, 0, 0, 0);
      aB3 = __builtin_amdgcn_mfma_f32_16x16x32_bf16(fB, b3, aB3, 0, 0, 0);
    }

    __syncthreads();   // ALL waves done reading kke before any Ke overwrite

    const int rA = rgA * 16 + lg * 4;
    const int rB = rgB * 16 + lg * 4;
    const int cb = cg * 64 + lr;
    #pragma unroll
    for (int r = 0; r < 4; ++r) {
      buf[(rA + r) * 136 + cb +  0] = f2bf(aA0[r]);
      buf[(rA + r) * 136 + cb + 16] = f2bf(aA1[r]);
      buf[(rA + r) * 136 + cb + 32] = f2bf(aA2[r]);
      buf[(rA + r) * 136 + cb + 48] = f2bf(aA3[r]);
      buf[(rB + r) * 136 + cb +  0] = f2bf(aB0[r]);
      buf[(rB + r) * 136 + cb + 16] = f2bf(aB1[r]);
      buf[(rB + r) * 136 + cb + 32] = f2bf(aB2[r]);
      buf[(rB + r) * 136 + cb + 48] = f2bf(aB3[r]);
    }
  }
  __syncthreads();   // Ke ready

  // ---- phase 2a: scores + softmax for both edges (reads Ke + Q regs) ----
  float sc0[8], sc1[8];
  {
    #pragma unroll
    for (int g = 0; g < 8; ++g) {
      const ushort8v* kp = (const ushort8v*)&buf[i0 * 136 + g * DKK];
      ushort8v k0 = kp[0], k1 = kp[1];
      float a = 0.0f;
      #pragma unroll
      for (int t = 0; t < 8; ++t) a = fmaf(bf2f(qa0[t]), bf2f(k0[t]), a);
      #pragma unroll
      for (int t = 0; t < 8; ++t) a = fmaf(bf2f(qa1[t]), bf2f(k1[t]), a);
      a *= 0.25f;
      sc0[g] = (a >= 0.0f) ? a : 0.01f * a;
    }
    #pragma unroll
    for (int g = 0; g < 8; ++g) {
      const ushort8v* kp = (const ushort8v*)&buf[i1 * 136 + g * DKK];
      ushort8v k0 = kp[0], k1 = kp[1];
      float a = 0.0f;
      #pragma unroll
      for (int t = 0; t < 8; ++t) a = fmaf(bf2f(qb0[t]), bf2f(k0[t]), a);
      #pragma unroll
      for (int t = 0; t < 8; ++t) a = fmaf(bf2f(qb1[t]), bf2f(k1[t]), a);
      a *= 0.25f;
      sc1[g] = (a >= 0.0f) ? a : 0.01f * a;
    }
    float mx0 = sc0[0], mx1 = sc1[0];
    #pragma unroll
    for (int g = 1; g < 8; ++g) { mx0 = fmaxf(mx0, sc0[g]); mx1 = fmaxf(mx1, sc1[g]); }
    float su0 = 0.0f, su1 = 0.0f;
    #pragma unroll
    for (int g = 0; g < 8; ++g) {
      sc0[g] = __expf(sc0[g] - mx0); su0 += sc0[g];
      sc1[g] = __expf(sc1[g] - mx1); su1 += sc1[g];
    }
    float r0 = 1.0f / su0, r1 = 1.0f / su1;
    #pragma unroll
    for (int g = 0; g < 8; ++g) { sc0[g] *= r0; sc1[g] *= r1; }
  }
  __syncthreads();   // all Ke reads done -> He may overwrite buf

  // ---- phase 2b: He = A @ Ve (V from LDS), stored bf16 in buf ----
  {
    float he[16];
    #pragma unroll
    for (int d = 0; d < 16; ++d) he[d] = 0.0f;
    #pragma unroll
    for (int g = 0; g < 8; ++g) {
      float a = sc0[g];
      const ushort8v* vp = (const ushort8v*)&vbuf[i0 * 136 + g * DKK];
      ushort8v v0 = vp[0], v1 = vp[1];
      #pragma unroll
      for (int t = 0; t < 8; ++t) {
        he[t]     = fmaf(a, bf2f(v0[t]), he[t]);
        he[8 + t] = fmaf(a, bf2f(v1[t]), he[8 + t]);
      }
    }
    ushort8v o0, o1;
    #pragma unroll
    for (int t = 0; t < 8; ++t) { o0[t] = f2bf(he[t]); o1[t] = f2bf(he[8 + t]); }
    *(ushort8v*)&buf[i0 * 136 + h * DKK]     = o0;
    *(ushort8v*)&buf[i0 * 136 + h * DKK + 8] = o1;

    #pragma unroll
    for (int d = 0; d < 16; ++d) he[d] = 0.0f;
    #pragma unroll
    for (int g = 0; g < 8; ++g) {
      float a = sc1[g];
      const ushort8v* vp = (const ushort8v*)&vbuf[i1 * 136 + g * DKK];
      ushort8v v0 = vp[0], v1 = vp[1];
      #pragma unroll
      for (int t = 0; t < 8; ++t) {
        he[t]     = fmaf(a, bf2f(v0[t]), he[t]);
        he[8 + t] = fmaf(a, bf2f(v1[t]), he[8 + t]);
      }
    }
    #pragma unroll
    for (int t = 0; t < 8; ++t) { o0[t] = f2bf(he[t]); o1[t] = f2bf(he[8 + t]); }
    *(ushort8v*)&buf[i1 * 136 + h * DKK]     = o0;
    *(ushort8v*)&buf[i1 * 136 + h * DKK + 8] = o1;
  }
  __syncthreads();

  // ---- parallel chunked flush: 8 chunks x 16 edges, paired b32 reads ----
  {
    const int c = tid >> 6, d2 = tid & 63;    // col pair 2*d2, 2*d2+1
    const int base = c * 16;
    float s0 = 0.0f, s1 = 0.0f;
    int curd = s_dst[base];
    #pragma unroll 8
    for (int j = 0; j < 16; ++j) {
      int i2 = base + j;
      int dn2 = s_dst[i2];
      if (dn2 != curd) {
        atomicAdd(&out[(size_t)curd * DD + d2 * 2],     s0);
        atomicAdd(&out[(size_t)curd * DD + d2 * 2 + 1], s1);
        s0 = 0.0f; s1 = 0.0f;
        curd = dn2;
      }
      unsigned int w = *(const unsigned int*)&buf[i2 * 136 + d2 * 2];
      s0 += bf2f((unsigned short)(w & 0xffff));
      s1 += bf2f((unsigned short)(w >> 16));
    }
    atomicAdd(&out[(size_t)curd * DD + d2 * 2],     s0);
    atomicAdd(&out[(size_t)curd * DD + d2 * 2 + 1], s1);
  }
}

// ---------------------------------------------------------------------------
extern "C" void kernel_launch(void* const* d_in, const int* in_sizes, int n_in,
                              void* d_out, int out_size, void* d_ws, size_t ws_size,
                              hipStream_t stream) {
  const float* q  = (const float*)d_in[0];
  const float* k  = (const float*)d_in[1];
  const float* v  = (const float*)d_in[2];
  const float* e  = (const float*)d_in[3];
  const int*   src = (const int*)d_in[4];
  const int*   dst = (const int*)d_in[5];
  const float* Wq = (const float*)d_in[6];
  const float* Wk = (const float*)d_in[7];
  const float* Wv = (const float*)d_in[8];

  float* out = (float*)d_out;
  char* wsb = (char*)d_ws;
  unsigned short* Qh  = (unsigned short*)wsb;                      // 12.8 MB
  unsigned short* Vh  = Qh + (size_t)NN * DD;                      // 12.8 MB
  unsigned short* kh  = Vh + (size_t)NN * DD;                      // 12.8 MB
  unsigned short* WqT = kh + (size_t)NN * DD;                      // 32 KB each
  unsigned short* WkT = WqT + DD * DD;
  unsigned short* WvT = WkT + DD * DD;
  int* cnt    = (int*)(WvT + DD * DD);                             // [NN]
  int* cur    = cnt + NN;                                          // [NN]
  int* rowptr = cur + NN;                                          // [NN+1]
  int* bsum   = rowptr + NN + 1;                                   // [64]
  int* bpre   = bsum + 64;                                         // [64]
  int* perm   = bpre + 64;                                         // [EE]

  hipMemsetAsync(d_out, 0, (size_t)NN * DD * sizeof(float), stream);
  hipMemsetAsync(cnt, 0, 2 * NN * sizeof(int), stream);            // cnt + cur

  hist_kernel <<<(EE / 4 + 255) / 256, 256, 0, stream>>>(dst, cnt);
  scan1_kernel<<<SCAN_NB, 256, 0, stream>>>(cnt, bsum);
  scan2_kernel<<<1, 64, 0, stream>>>(bsum, bpre);
  scan3_kernel<<<SCAN_NB, 256, 0, stream>>>(cnt, bpre, rowptr);
  fill_kernel <<<(EE / 4 + 255) / 256, 256, 0, stream>>>(dst, rowptr, cur, perm);

  prep_w_kernel<<<3 * DD, DD, 0, stream>>>(Wq, Wk, Wv, WqT, WkT, WvT);
  node_proj_kernel<<<(NN + 63) / 64, 512, 0, stream>>>(q, v, k, WqT, WvT,
                                                       Qh, Vh, kh);
  edge_attn_kernel<<<EE / 128, 512, 0, stream>>>(kh, e, src, dst, perm,
                                                 WkT, Qh, Vh, out);
}